// Round 11
// baseline (197.471 us; speedup 1.0000x reference)
//
#include <hip/hip_runtime.h>

typedef __attribute__((ext_vector_type(8))) short short8;
typedef __attribute__((ext_vector_type(4))) short s16x4;
typedef __attribute__((ext_vector_type(8))) __bf16 bf16x8;
typedef __attribute__((ext_vector_type(4))) __bf16 bf16x4;
typedef __attribute__((ext_vector_type(2))) __bf16 bf16x2;
typedef __attribute__((ext_vector_type(4))) float f32x4;
typedef __attribute__((ext_vector_type(2))) float f32x2;
typedef __attribute__((ext_vector_type(4))) unsigned uint4v;
typedef __attribute__((ext_vector_type(2))) unsigned uint2v;

__device__ inline f32x4 mfma_bf16(short8 a, short8 b, f32x4 c) {
    return __builtin_amdgcn_mfma_f32_16x16x32_bf16(
        __builtin_bit_cast(bf16x8, a), __builtin_bit_cast(bf16x8, b), c, 0, 0, 0);
}
// K=16 bf16 MFMA: A-frag layout A[m=l16][k=quad*4+j] == C/D layout of a prior
// MFMA transposed -> P needs no layout transform.
__device__ inline f32x4 mfma16(uint2v a, uint2v b, f32x4 c) {
#if __has_builtin(__builtin_amdgcn_mfma_f32_16x16x16_bf16)
    return __builtin_amdgcn_mfma_f32_16x16x16_bf16(
        __builtin_bit_cast(bf16x4, a), __builtin_bit_cast(bf16x4, b), c, 0, 0, 0);
#else
    return __builtin_amdgcn_mfma_f32_16x16x16bf16_1k(
        __builtin_bit_cast(s16x4, a), __builtin_bit_cast(s16x4, b), c, 0, 0, 0);
#endif
}

// fast exp2: bare v_exp_f32
__device__ inline float fexp2(float x) {
#if __has_builtin(__builtin_amdgcn_exp2f)
    return __builtin_amdgcn_exp2f(x);
#else
    return exp2f(x);
#endif
}

// fp32 -> bf16 via HW convert (v_cvt_pk_bf16_f32 on gfx950), RNE
__device__ inline short f2b(float f) {
    __bf16 h = (__bf16)f;
    return __builtin_bit_cast(short, h);
}
__device__ inline unsigned pkbf(float a, float b) {
    f32x2 v; v[0] = a; v[1] = b;
    bf16x2 h = __builtin_convertvector(v, bf16x2);
    return __builtin_bit_cast(unsigned, h);
}

__device__ inline short8 ld8(const short* p) { return *(const short8*)p; }
__device__ inline short8 ld8(const float* p) {
    f32x4 a = *(const f32x4*)p;
    f32x4 b = *(const f32x4*)(p + 4);
    uint4v q;
    q[0] = pkbf(a[0], a[1]); q[1] = pkbf(a[2], a[3]);
    q[2] = pkbf(b[0], b[1]); q[3] = pkbf(b[2], b[3]);
    return __builtin_bit_cast(short8, q);
}
__device__ inline void storeC(short* C, size_t i, float v) { C[i] = f2b(v); }
__device__ inline void storeC(float* C, size_t i, float v) { C[i] = v; }

// async global->LDS DMA, 16B per lane. LDS dest must be wave-uniform base;
// HW writes lane l at base + l*16 (m104/m108: no per-lane LDS scatter).
__device__ inline void gload16(const short* g, short* l) {
    __builtin_amdgcn_global_load_lds(
        (const __attribute__((address_space(1))) unsigned*)g,
        (__attribute__((address_space(3))) unsigned*)l, 16, 0, 0);
}

// log2(e)/32 : folded into Q so softmax uses exp2 (bare v_exp_f32)
#define QSCALE 0.04508422052265167f

// ---------------------------------------------------------------------------
// Fused prep: one launch does
//   blocks [0,2048):    x fp32 -> xbf bf16 bulk convert
//   blocks [2048,2816): Wqkv [1024][3072] -> wqkvt [3072][1024] bf16 k-major
//   blocks [2816,3072): Wout [1024][1024] -> woutt [1024][1024] bf16 k-major
// ---------------------------------------------------------------------------
__global__ __launch_bounds__(256) void prep(
    const float* __restrict__ x, short* __restrict__ xb,
    const float* __restrict__ Wqkv, short* __restrict__ wqkvt,
    const float* __restrict__ Wout, short* __restrict__ woutt)
{
    const int bid = blockIdx.x;
    const int tid = threadIdx.x;
    if (bid < 2048) {
        size_t i = ((size_t)bid * 256 + tid) * 8;
        *(short8*)(xb + i) = ld8(x + i);
        return;
    }
    __shared__ short T[64 * 72];
    const float* W; short* Wt; int K, N, n0, k0;
    if (bid < 2816) {
        const int b2 = bid - 2048;
        W = Wqkv; Wt = wqkvt; K = 1024; N = 3072;
        n0 = (b2 % 48) * 64; k0 = (b2 / 48) * 64;
    } else {
        const int b3 = bid - 2816;
        W = Wout; Wt = woutt; K = 1024; N = 1024;
        n0 = (b3 & 15) * 64; k0 = (b3 >> 4) * 64;
    }
    {
        const int kl = tid >> 2, nc = (tid & 3) * 16;
        const float* src = W + (size_t)(k0 + kl) * N + n0 + nc;
        float v[16];
        *(f32x4*)&v[0]  = *(const f32x4*)(src + 0);
        *(f32x4*)&v[4]  = *(const f32x4*)(src + 4);
        *(f32x4*)&v[8]  = *(const f32x4*)(src + 8);
        *(f32x4*)&v[12] = *(const f32x4*)(src + 12);
        #pragma unroll
        for (int j = 0; j < 16; ++j) T[(nc + j) * 72 + kl] = f2b(v[j]);
    }
    __syncthreads();
    {
        const int nl = tid >> 2, kc = (tid & 3) * 16;
        short8 w0 = *(const short8*)&T[nl * 72 + kc];
        short8 w1 = *(const short8*)&T[nl * 72 + kc + 8];
        short* dst = Wt + (size_t)(n0 + nl) * K + k0 + kc;
        *(short8*)dst = w0;
        *(short8*)(dst + 8) = w1;
    }
}

// ---------------------------------------------------------------------------
// V transpose: qkv (B*N,3072) bf16 cols 2048+h*64 -> vt[(b*16+h)][dim][2048].
// ---------------------------------------------------------------------------
__global__ __launch_bounds__(256) void vtrans(
    const short* __restrict__ qkv, short* __restrict__ vt)
{
    __shared__ short T[64 * 72];
    const int tid = threadIdx.x;
    const int nt = blockIdx.x * 64, bh = blockIdx.y;
    const int b = bh >> 4, h = bh & 15;
    {
        const int tok = tid >> 2, dc = (tid & 3) * 16;
        const short* src = qkv + ((size_t)b * 2048 + nt + tok) * 3072 + 2048 + h * 64 + dc;
        short8 v0 = *(const short8*)src;
        short8 v1 = *(const short8*)(src + 8);
        #pragma unroll
        for (int j = 0; j < 8; ++j) {
            T[(dc + j) * 72 + tok]     = v0[j];
            T[(dc + 8 + j) * 72 + tok] = v1[j];
        }
    }
    __syncthreads();
    {
        const int dim = tid >> 2, kc = (tid & 3) * 16;
        short8 w0 = *(const short8*)&T[dim * 72 + kc];
        short8 w1 = *(const short8*)&T[dim * 72 + kc + 8];
        short* dst = vt + ((size_t)bh * 64 + dim) * 2048 + nt + kc;
        *(short8*)dst = w0;
        *(short8*)(dst + 8) = w1;
    }
}

// ---------------------------------------------------------------------------
// GEMM: global_load_lds DMA staging + double-buffered LDS 2-phase pipeline.
// C = A @ Bt^T (+bias). 128x128 tile, BK=32, 4 waves 2x2 (64x64 each).
// + T1 XCD-aware block swizzle (nwg%8==0 at both call sites; bijective):
//   XCD r (dispatch id ≡ r mod 8) gets contiguous work ids -> neighboring
//   tiles share A-panels in that XCD's private L2.
// ---------------------------------------------------------------------------
template <bool QSC, bool ADD_BIAS, typename TC>
__global__ __launch_bounds__(256, 4) void gemm128(
    const short* __restrict__ A, const short* __restrict__ Bt,
    const float* __restrict__ bias, TC* __restrict__ C,
    int M, int N, int K, int lda)
{
    __shared__ short A_s0[128 * 32];
    __shared__ short A_s1[128 * 32];
    __shared__ short B_s0[128 * 32];
    __shared__ short B_s1[128 * 32];
    const int tid  = threadIdx.x;
    const int lane = tid & 63;
    const int wave = tid >> 6;
    const int quad = lane >> 4;
    const int l16  = lane & 15;
    const int wr   = wave >> 1;
    const int wc   = wave & 1;
    // XCD swizzle: id = y*gx + x; sid = (id%8)*(nwg/8) + id/8
    const int nwg = gridDim.x * gridDim.y;
    const int lid = blockIdx.y * gridDim.x + blockIdx.x;
    const int sid = (lid & 7) * (nwg >> 3) + (lid >> 3);
    const int bm  = (sid / gridDim.x) * 128;
    const int bn  = (sid % gridDim.x) * 128;

    f32x4 acc[4][4];
    #pragma unroll
    for (int i = 0; i < 4; ++i)
        #pragma unroll
        for (int j = 0; j < 4; ++j)
            acc[i][j] = f32x4{0.f, 0.f, 0.f, 0.f};

    const int srow = tid >> 2;
    const int schk = tid & 3;
    const int sg   = (schk ^ ((srow >> 1) & 3)) * 8;
    const short* ap0 = A  + (size_t)(bm + srow) * lda + sg;
    const short* ap1 = A  + (size_t)(bm + 64 + srow) * lda + sg;
    const short* bp0 = Bt + (size_t)(bn + srow) * K   + sg;
    const short* bp1 = Bt + (size_t)(bn + 64 + srow) * K   + sg;
    const int lofs0 = wave * 512;
    const int lofs1 = 2048 + wave * 512;

    const int xr = (quad ^ ((l16 >> 1) & 3)) * 8;

#define STAGE_G(As, Bs, koff)                  \
    gload16(ap0 + (koff), (As) + lofs0);       \
    gload16(ap1 + (koff), (As) + lofs1);       \
    gload16(bp0 + (koff), (Bs) + lofs0);       \
    gload16(bp1 + (koff), (Bs) + lofs1);

#define COMPUTE_G(As, Bs)                                                   \
    {                                                                       \
        short8 a[4], b[4];                                                  \
        _Pragma("unroll")                                                   \
        for (int i = 0; i < 4; ++i)                                         \
            a[i] = *(const short8*)&(As)[(wr * 64 + i * 16 + l16) * 32 + xr]; \
        _Pragma("unroll")                                                   \
        for (int j = 0; j < 4; ++j)                                         \
            b[j] = *(const short8*)&(Bs)[(wc * 64 + j * 16 + l16) * 32 + xr]; \
        _Pragma("unroll")                                                   \
        for (int i = 0; i < 4; ++i)                                         \
            _Pragma("unroll")                                               \
            for (int j = 0; j < 4; ++j)                                     \
                acc[i][j] = mfma_bf16(a[i], b[j], acc[i][j]);               \
    }

    STAGE_G(A_s0, B_s0, 0);
    __syncthreads();

    for (int k0 = 0; k0 < K; k0 += 64) {
        if (k0 + 32 < K) { STAGE_G(A_s1, B_s1, k0 + 32); }
        COMPUTE_G(A_s0, B_s0);
        __syncthreads();
        if (k0 + 64 < K) { STAGE_G(A_s0, B_s0, k0 + 64); }
        COMPUTE_G(A_s1, B_s1);
        __syncthreads();
    }
#undef STAGE_G
#undef COMPUTE_G

    const float scale = (QSC && bn < 1024) ? QSCALE : 1.0f;
    #pragma unroll
    for (int i = 0; i < 4; ++i) {
        #pragma unroll
        for (int j = 0; j < 4; ++j) {
            #pragma unroll
            for (int r = 0; r < 4; ++r) {
                int row = bm + wr * 64 + i * 16 + quad * 4 + r;
                int col = bn + wc * 64 + j * 16 + l16;
                float v = acc[i][j][r] * scale;
                if (ADD_BIAS) v += bias[col];
                storeC(C, (size_t)row * N + col, v);
            }
        }
    }
}

// ---------------------------------------------------------------------------
// gemm64: BM=64, BN=128 variant of the same structure for the out-proj GEMM.
// Grid (8, 64) = 512 blocks -> 2 blocks/CU. 4 waves 2x2, per-wave 32x64.
// + T1 XCD swizzle (512 % 8 == 0).
// ---------------------------------------------------------------------------
template <bool ADD_BIAS, typename TC>
__global__ __launch_bounds__(256, 4) void gemm64(
    const short* __restrict__ A, const short* __restrict__ Bt,
    const float* __restrict__ bias, TC* __restrict__ C,
    int M, int N, int K, int lda)
{
    __shared__ short A_s0[64 * 32];
    __shared__ short A_s1[64 * 32];
    __shared__ short B_s0[128 * 32];
    __shared__ short B_s1[128 * 32];
    const int tid  = threadIdx.x;
    const int lane = tid & 63;
    const int wave = tid >> 6;
    const int quad = lane >> 4;
    const int l16  = lane & 15;
    const int wr   = wave >> 1;     // M half (32 rows)
    const int wc   = wave & 1;      // N half (64 cols)
    const int nwg = gridDim.x * gridDim.y;
    const int lid = blockIdx.y * gridDim.x + blockIdx.x;
    const int sid = (lid & 7) * (nwg >> 3) + (lid >> 3);
    const int bm  = (sid / gridDim.x) * 64;
    const int bn  = (sid % gridDim.x) * 128;

    f32x4 acc[2][4];
    #pragma unroll
    for (int i = 0; i < 2; ++i)
        #pragma unroll
        for (int j = 0; j < 4; ++j)
            acc[i][j] = f32x4{0.f, 0.f, 0.f, 0.f};

    const int srow = tid >> 2;
    const int schk = tid & 3;
    const int sg   = (schk ^ ((srow >> 1) & 3)) * 8;
    const short* ap0 = A  + (size_t)(bm + srow) * lda + sg;
    const short* bp0 = Bt + (size_t)(bn + srow) * K   + sg;
    const short* bp1 = Bt + (size_t)(bn + 64 + srow) * K + sg;
    const int lofs0 = wave * 512;
    const int lofs1 = 2048 + wave * 512;

    const int xr = (quad ^ ((l16 >> 1) & 3)) * 8;

#define STAGE_H(As, Bs, koff)                  \
    gload16(ap0 + (koff), (As) + lofs0);       \
    gload16(bp0 + (koff), (Bs) + lofs0);       \
    gload16(bp1 + (koff), (Bs) + lofs1);

#define COMPUTE_H(As, Bs)                                                   \
    {                                                                       \
        short8 a[2], b[4];                                                  \
        _Pragma("unroll")                                                   \
        for (int i = 0; i < 2; ++i)                                         \
            a[i] = *(const short8*)&(As)[(wr * 32 + i * 16 + l16) * 32 + xr]; \
        _Pragma("unroll")                                                   \
        for (int j = 0; j < 4; ++j)                                         \
            b[j] = *(const short8*)&(Bs)[(wc * 64 + j * 16 + l16) * 32 + xr]; \
        _Pragma("unroll")                                                   \
        for (int i = 0; i < 2; ++i)                                         \
            _Pragma("unroll")                                               \
            for (int j = 0; j < 4; ++j)                                     \
                acc[i][j] = mfma_bf16(a[i], b[j], acc[i][j]);               \
    }

    STAGE_H(A_s0, B_s0, 0);
    __syncthreads();

    for (int k0 = 0; k0 < K; k0 += 64) {
        if (k0 + 32 < K) { STAGE_H(A_s1, B_s1, k0 + 32); }
        COMPUTE_H(A_s0, B_s0);
        __syncthreads();
        if (k0 + 64 < K) { STAGE_H(A_s0, B_s0, k0 + 64); }
        COMPUTE_H(A_s1, B_s1);
        __syncthreads();
    }
#undef STAGE_H
#undef COMPUTE_H

    #pragma unroll
    for (int i = 0; i < 2; ++i) {
        #pragma unroll
        for (int j = 0; j < 4; ++j) {
            #pragma unroll
            for (int r = 0; r < 4; ++r) {
                int row = bm + wr * 32 + i * 16 + quad * 4 + r;
                int col = bn + wc * 64 + j * 16 + l16;
                float v = acc[i][j][r];
                if (ADD_BIAS) v += bias[col];
                storeC(C, (size_t)row * N + col, v);
            }
        }
    }
}

// ---------------------------------------------------------------------------
// Flash attention v10 = v7 compute + DOUBLE-BUFFERED K/V LDS, 1 barrier/tile.
// Why: __syncthreads drains vmcnt(0) (compiler barrier semantics). v7's
// order {stage-writes; prefetch(t+1); barrier; compute} drained the JUST-
// ISSUED prefetch at the barrier -> full load latency exposed every tile,
// plus the write phase was serialized between two barriers. v10 order:
//   stage(t+1 -> buf^1)   // regs loaded LAST iteration, long landed
//   prefetch(t+2)         // issue early; lands during compute below
//   compute(t, buf)       // heavy phase covers load latency
//   barrier               // cheap drain; publishes buf^1
// Hazards: WAR on buf^1 protected by the barrier ending tile t-1 (its
// readers finished there); RAW on buf by the same barrier; reg reuse by
// program order. LDS 2x35KB = 70.1KB -> still 2 blocks/CU (unchanged).
// Key-split (v9/v9b) refuted: lockstep waves stall together; TLP at equal
// per-CU LDS traffic gained nothing (60.4 vs 57.6 baseline).
// grid (2048/128, 32) = 512 blocks, 256 threads.
// ---------------------------------------------------------------------------
__global__ __launch_bounds__(256) void attn128(
    short* __restrict__ qkv, const short* __restrict__ vt)
{
    __shared__ short Ks0[128 * 72];
    __shared__ short Vs0[16 * 520];
    __shared__ short Ks1[128 * 72];
    __shared__ short Vs1[16 * 520];

    const int tid  = threadIdx.x;
    const int lane = tid & 63;
    const int wave = tid >> 6;
    const int quad = lane >> 4;
    const int l16  = lane & 15;
    const int bh   = blockIdx.y, b = bh >> 4, h = bh & 15;
    const int qb   = blockIdx.x * 128;
    const size_t rowbase = (size_t)b * 2048;

    // Q fragments for 2 q-groups (B-op for S^T), pre-scaled by log2e/32
    short8 aq[2][2];
    #pragma unroll
    for (int qg = 0; qg < 2; ++qg) {
        const short* qp = qkv + (rowbase + qb + wave * 32 + qg * 16 + l16) * 3072 + h * 64;
        aq[qg][0] = *(const short8*)(qp + quad * 8);
        aq[qg][1] = *(const short8*)(qp + 32 + quad * 8);
    }

    f32x4 o[2][4];
    #pragma unroll
    for (int qg = 0; qg < 2; ++qg)
        #pragma unroll
        for (int c = 0; c < 4; ++c) o[qg][c] = f32x4{0.f, 0.f, 0.f, 0.f};
    float rsum[2] = {0.f, 0.f};   // softmax denom partials for q = l16

    const int kkey = tid >> 1, kdc = (tid & 1) * 32;
    const int vdim = tid >> 2, vg0 = (tid & 3) * 4;
    const short* kbase = qkv + (rowbase + kkey) * 3072 + 1024 + h * 64 + kdc;
    const short* vbase = vt + ((size_t)bh * 64 + vdim) * 2048 + vg0 * 8;

    short8 kr0, kr1, kr2, kr3, vr0, vr1, vr2, vr3;

    auto prefetch = [&](int kt) {
        const short* kp = kbase + (size_t)kt * 3072;
        kr0 = *(const short8*)(kp);
        kr1 = *(const short8*)(kp + 8);
        kr2 = *(const short8*)(kp + 16);
        kr3 = *(const short8*)(kp + 24);
        const short* vp = vbase + kt;
        vr0 = *(const short8*)(vp);
        vr1 = *(const short8*)(vp + 8);
        vr2 = *(const short8*)(vp + 16);
        vr3 = *(const short8*)(vp + 24);
    };
    auto stage = [&](short* Ks, short* Vs) {
        *(short8*)&Ks[kkey * 72 + kdc]      = kr0;
        *(short8*)&Ks[kkey * 72 + kdc + 8]  = kr1;
        *(short8*)&Ks[kkey * 72 + kdc + 16] = kr2;
        *(short8*)&Ks[kkey * 72 + kdc + 24] = kr3;
        *(short8*)&Vs[(vg0 + 0) * 520 + vdim * 8] = vr0;
        *(short8*)&Vs[(vg0 + 1) * 520 + vdim * 8] = vr1;
        *(short8*)&Vs[(vg0 + 2) * 520 + vdim * 8] = vr2;
        *(short8*)&Vs[(vg0 + 3) * 520 + vdim * 8] = vr3;
    };
    auto compute = [&](const short* Ks, const short* Vs) {
        #pragma unroll
        for (int cc = 0; cc < 2; ++cc) {
            // S^T: lane holds S[q=l16][key=(cc*4+c4)*16+quad*4+r], per q-group
            f32x4 st[2][4];
            #pragma unroll
            for (int c4 = 0; c4 < 4; ++c4) {
                const int c = cc * 4 + c4;
                short8 ka0 = *(const short8*)&Ks[(c * 16 + l16) * 72 + quad * 8];
                short8 ka1 = *(const short8*)&Ks[(c * 16 + l16) * 72 + 32 + quad * 8];
                #pragma unroll
                for (int qg = 0; qg < 2; ++qg) {
                    f32x4 z = f32x4{0.f, 0.f, 0.f, 0.f};
                    z = mfma_bf16(ka0, aq[qg][0], z);
                    st[qg][c4] = mfma_bf16(ka1, aq[qg][1], z);
                }
            }
            // p = exp2(s'): bare v_exp_f32 + v_cvt_pk_bf16_f32 packing
            uint2v pa[2][4];
            #pragma unroll
            for (int qg = 0; qg < 2; ++qg) {
                #pragma unroll
                for (int c4 = 0; c4 < 4; ++c4) {
                    float p0 = fexp2(st[qg][c4][0]);
                    float p1 = fexp2(st[qg][c4][1]);
                    float p2 = fexp2(st[qg][c4][2]);
                    float p3 = fexp2(st[qg][c4][3]);
                    rsum[qg] += (p0 + p1) + (p2 + p3);
                    uint2v pk;
                    pk[0] = pkbf(p0, p1);
                    pk[1] = pkbf(p2, p3);
                    pa[qg][c4] = pk;
                }
            }
            // PV: bv read once, used by both q-groups
            #pragma unroll
            for (int c2 = 0; c2 < 4; ++c2) {
                #pragma unroll
                for (int c4 = 0; c4 < 4; ++c4) {
                    const int c = cc * 4 + c4;
                    uint2v bv = *(const uint2v*)&Vs[(2 * c + (quad >> 1)) * 520
                                                    + (c2 * 16 + l16) * 8
                                                    + (quad & 1) * 4];
                    #pragma unroll
                    for (int qg = 0; qg < 2; ++qg)
                        o[qg][c2] = mfma16(pa[qg][c4], bv, o[qg][c2]);
                }
            }
        }
    };

    // prologue: tile0 -> buf0, regs <- tile1
    prefetch(0);
    stage(Ks0, Vs0);
    prefetch(128);
    __syncthreads();

    // 16 tiles, dbuf, 1 barrier per tile (2x unrolled for static buffers)
    for (int t = 0; t < 16; t += 2) {
        stage(Ks1, Vs1);                       // tile t+1 (regs from last iter)
        if (t + 2 < 16) prefetch((t + 2) * 128);
        compute(Ks0, Vs0);                     // tile t
        __syncthreads();
        if (t + 2 < 16) stage(Ks0, Vs0);       // tile t+2
        if (t + 3 < 16) prefetch((t + 3) * 128);
        compute(Ks1, Vs1);                     // tile t+1
        __syncthreads();
    }

    // full denom for q=l16: sum over the 4 quad-lanes
    #pragma unroll
    for (int qg = 0; qg < 2; ++qg) {
        rsum[qg] += __shfl_xor(rsum[qg], 16, 64);
        rsum[qg] += __shfl_xor(rsum[qg], 32, 64);
    }

    // epilogue: o rows are q=quad*4+r; fetch that q's denom from lane q
    #pragma unroll
    for (int qg = 0; qg < 2; ++qg) {
        #pragma unroll
        for (int r = 0; r < 4; ++r) {
            float inv = 1.0f / __shfl(rsum[qg], quad * 4 + r, 64);
            size_t row = rowbase + qb + wave * 32 + qg * 16 + quad * 4 + r;
            #pragma unroll
            for (int c2 = 0; c2 < 4; ++c2)
                qkv[row * 3072 + h * 64 + c2 * 16 + l16] = f2b(o[qg][c2][r] * inv);
        }
    }
}

// ---------------------------------------------------------------------------
extern "C" void kernel_launch(void* const* d_in, const int* in_sizes, int n_in,
                              void* d_out, int out_size, void* d_ws, size_t ws_size,
                              hipStream_t stream)
{
    const float* x    = (const float*)d_in[0];   // (2,2048,1024) fp32
    const float* Wqkv = (const float*)d_in[2];   // (1024,3072) fp32
    const float* Wout = (const float*)d_in[3];   // (1024,1024) fp32
    const float* bout = (const float*)d_in[4];   // (1024,) fp32
    float* out = (float*)d_out;                  // (2,2048,1024) fp32

    // Buffer map:
    //   ws (32 MiB): qkv 24 MiB | wqkvt 6 MiB | woutt 2 MiB
    //   d_out (16 MiB): xbf lower 8 MiB (dead after gemm1)
    //                   vt  upper 8 MiB (dead after attn)
    //   gemm2 overwrites all of d_out last.
    short* qkv   = (short*)d_ws;                        // 4096 x 3072 bf16
    short* wqkvt = qkv + (size_t)4096 * 3072;           // 3072 x 1024 bf16
    short* woutt = wqkvt + (size_t)3072 * 1024;         // 1024 x 1024 bf16
    short* xbf   = (short*)d_out;                       // 4096 x 1024 bf16
    short* vtbuf = xbf + (size_t)4096 * 1024;           // 32 x 64 x 2048 bf16

    dim3 blk(256);
    prep<<<dim3(3072), blk, 0, stream>>>(x, xbf, Wqkv, wqkvt, Wout, woutt);
    gemm128<true, false, short><<<dim3(24, 32), blk, 0, stream>>>(
        xbf, wqkvt, nullptr, qkv, 4096, 3072, 1024, 1024);
    vtrans<<<dim3(32, 32), blk, 0, stream>>>(qkv, vtbuf);
    attn128<<<dim3(16, 32), blk, 0, stream>>>(qkv, vtbuf);
    gemm64<true, float><<<dim3(8, 64), blk, 0, stream>>>(
        qkv, woutt, bout, out, 4096, 1024, 1024, 3072);
}

// Round 12
// 191.237 us; speedup vs baseline: 1.0326x; 1.0326x over previous
//
#include <hip/hip_runtime.h>

typedef __attribute__((ext_vector_type(8))) short short8;
typedef __attribute__((ext_vector_type(4))) short s16x4;
typedef __attribute__((ext_vector_type(8))) __bf16 bf16x8;
typedef __attribute__((ext_vector_type(4))) __bf16 bf16x4;
typedef __attribute__((ext_vector_type(2))) __bf16 bf16x2;
typedef __attribute__((ext_vector_type(4))) float f32x4;
typedef __attribute__((ext_vector_type(2))) float f32x2;
typedef __attribute__((ext_vector_type(4))) unsigned uint4v;
typedef __attribute__((ext_vector_type(2))) unsigned uint2v;

__device__ inline f32x4 mfma_bf16(short8 a, short8 b, f32x4 c) {
    return __builtin_amdgcn_mfma_f32_16x16x32_bf16(
        __builtin_bit_cast(bf16x8, a), __builtin_bit_cast(bf16x8, b), c, 0, 0, 0);
}
// K=16 bf16 MFMA: A-frag layout A[m=l16][k=quad*4+j] == C/D layout of a prior
// MFMA transposed -> P needs no layout transform.
__device__ inline f32x4 mfma16(uint2v a, uint2v b, f32x4 c) {
#if __has_builtin(__builtin_amdgcn_mfma_f32_16x16x16_bf16)
    return __builtin_amdgcn_mfma_f32_16x16x16_bf16(
        __builtin_bit_cast(bf16x4, a), __builtin_bit_cast(bf16x4, b), c, 0, 0, 0);
#else
    return __builtin_amdgcn_mfma_f32_16x16x16bf16_1k(
        __builtin_bit_cast(s16x4, a), __builtin_bit_cast(s16x4, b), c, 0, 0, 0);
#endif
}

// fast exp2: bare v_exp_f32
__device__ inline float fexp2(float x) {
#if __has_builtin(__builtin_amdgcn_exp2f)
    return __builtin_amdgcn_exp2f(x);
#else
    return exp2f(x);
#endif
}

// fp32 -> bf16 via HW convert (v_cvt_pk_bf16_f32 on gfx950), RNE
__device__ inline short f2b(float f) {
    __bf16 h = (__bf16)f;
    return __builtin_bit_cast(short, h);
}
__device__ inline unsigned pkbf(float a, float b) {
    f32x2 v; v[0] = a; v[1] = b;
    bf16x2 h = __builtin_convertvector(v, bf16x2);
    return __builtin_bit_cast(unsigned, h);
}

__device__ inline short8 ld8(const short* p) { return *(const short8*)p; }
__device__ inline short8 ld8(const float* p) {
    f32x4 a = *(const f32x4*)p;
    f32x4 b = *(const f32x4*)(p + 4);
    uint4v q;
    q[0] = pkbf(a[0], a[1]); q[1] = pkbf(a[2], a[3]);
    q[2] = pkbf(b[0], b[1]); q[3] = pkbf(b[2], b[3]);
    return __builtin_bit_cast(short8, q);
}
__device__ inline void storeC(short* C, size_t i, float v) { C[i] = f2b(v); }
__device__ inline void storeC(float* C, size_t i, float v) { C[i] = v; }

// async global->LDS DMA, 16B per lane. LDS dest must be wave-uniform base;
// HW writes lane l at base + l*16 (m104/m108: no per-lane LDS scatter).
__device__ inline void gload16(const short* g, short* l) {
    __builtin_amdgcn_global_load_lds(
        (const __attribute__((address_space(1))) unsigned*)g,
        (__attribute__((address_space(3))) unsigned*)l, 16, 0, 0);
}

// log2(e)/32 : folded into Q so softmax uses exp2 (bare v_exp_f32)
#define QSCALE 0.04508422052265167f

// ---------------------------------------------------------------------------
// Fused prep: one launch does
//   blocks [0,2048):    x fp32 -> xbf bf16 bulk convert
//   blocks [2048,2816): Wqkv [1024][3072] -> wqkvt [3072][1024] bf16 k-major
//   blocks [2816,3072): Wout [1024][1024] -> woutt [1024][1024] bf16 k-major
// ---------------------------------------------------------------------------
__global__ __launch_bounds__(256) void prep(
    const float* __restrict__ x, short* __restrict__ xb,
    const float* __restrict__ Wqkv, short* __restrict__ wqkvt,
    const float* __restrict__ Wout, short* __restrict__ woutt)
{
    const int bid = blockIdx.x;
    const int tid = threadIdx.x;
    if (bid < 2048) {
        size_t i = ((size_t)bid * 256 + tid) * 8;
        *(short8*)(xb + i) = ld8(x + i);
        return;
    }
    __shared__ short T[64 * 72];
    const float* W; short* Wt; int K, N, n0, k0;
    if (bid < 2816) {
        const int b2 = bid - 2048;
        W = Wqkv; Wt = wqkvt; K = 1024; N = 3072;
        n0 = (b2 % 48) * 64; k0 = (b2 / 48) * 64;
    } else {
        const int b3 = bid - 2816;
        W = Wout; Wt = woutt; K = 1024; N = 1024;
        n0 = (b3 & 15) * 64; k0 = (b3 >> 4) * 64;
    }
    {
        const int kl = tid >> 2, nc = (tid & 3) * 16;
        const float* src = W + (size_t)(k0 + kl) * N + n0 + nc;
        float v[16];
        *(f32x4*)&v[0]  = *(const f32x4*)(src + 0);
        *(f32x4*)&v[4]  = *(const f32x4*)(src + 4);
        *(f32x4*)&v[8]  = *(const f32x4*)(src + 8);
        *(f32x4*)&v[12] = *(const f32x4*)(src + 12);
        #pragma unroll
        for (int j = 0; j < 16; ++j) T[(nc + j) * 72 + kl] = f2b(v[j]);
    }
    __syncthreads();
    {
        const int nl = tid >> 2, kc = (tid & 3) * 16;
        short8 w0 = *(const short8*)&T[nl * 72 + kc];
        short8 w1 = *(const short8*)&T[nl * 72 + kc + 8];
        short* dst = Wt + (size_t)(n0 + nl) * K + k0 + kc;
        *(short8*)dst = w0;
        *(short8*)(dst + 8) = w1;
    }
}

// ---------------------------------------------------------------------------
// V transpose: qkv (B*N,3072) bf16 cols 2048+h*64 -> vt[(b*16+h)][dim][2048].
// ---------------------------------------------------------------------------
__global__ __launch_bounds__(256) void vtrans(
    const short* __restrict__ qkv, short* __restrict__ vt)
{
    __shared__ short T[64 * 72];
    const int tid = threadIdx.x;
    const int nt = blockIdx.x * 64, bh = blockIdx.y;
    const int b = bh >> 4, h = bh & 15;
    {
        const int tok = tid >> 2, dc = (tid & 3) * 16;
        const short* src = qkv + ((size_t)b * 2048 + nt + tok) * 3072 + 2048 + h * 64 + dc;
        short8 v0 = *(const short8*)src;
        short8 v1 = *(const short8*)(src + 8);
        #pragma unroll
        for (int j = 0; j < 8; ++j) {
            T[(dc + j) * 72 + tok]     = v0[j];
            T[(dc + 8 + j) * 72 + tok] = v1[j];
        }
    }
    __syncthreads();
    {
        const int dim = tid >> 2, kc = (tid & 3) * 16;
        short8 w0 = *(const short8*)&T[dim * 72 + kc];
        short8 w1 = *(const short8*)&T[dim * 72 + kc + 8];
        short* dst = vt + ((size_t)bh * 64 + dim) * 2048 + nt + kc;
        *(short8*)dst = w0;
        *(short8*)(dst + 8) = w1;
    }
}

// ---------------------------------------------------------------------------
// GEMM: global_load_lds DMA staging + double-buffered LDS 2-phase pipeline.
// C = A @ Bt^T (+bias). 128x128 tile, BK=32, 4 waves 2x2 (64x64 each).
// STAGE(next) issued BEFORE COMPUTE(cur); one barrier per K-step.
// Bank-swizzle: source chunk c ^ ((row>>1)&3), read slot quad ^ ((l16>>1)&3).
// QSC: scale cols<1024 by log2(e)/32 (Q pre-scale for exp2 softmax).
// ---------------------------------------------------------------------------
template <bool QSC, bool ADD_BIAS, typename TC>
__global__ __launch_bounds__(256, 4) void gemm128(
    const short* __restrict__ A, const short* __restrict__ Bt,
    const float* __restrict__ bias, TC* __restrict__ C,
    int M, int N, int K, int lda)
{
    __shared__ short A_s0[128 * 32];
    __shared__ short A_s1[128 * 32];
    __shared__ short B_s0[128 * 32];
    __shared__ short B_s1[128 * 32];
    const int tid  = threadIdx.x;
    const int lane = tid & 63;
    const int wave = tid >> 6;
    const int quad = lane >> 4;
    const int l16  = lane & 15;
    const int wr   = wave >> 1;
    const int wc   = wave & 1;
    const int bm   = blockIdx.y * 128;
    const int bn   = blockIdx.x * 128;

    f32x4 acc[4][4];
    #pragma unroll
    for (int i = 0; i < 4; ++i)
        #pragma unroll
        for (int j = 0; j < 4; ++j)
            acc[i][j] = f32x4{0.f, 0.f, 0.f, 0.f};

    const int srow = tid >> 2;
    const int schk = tid & 3;
    const int sg   = (schk ^ ((srow >> 1) & 3)) * 8;
    const short* ap0 = A  + (size_t)(bm + srow) * lda + sg;
    const short* ap1 = A  + (size_t)(bm + 64 + srow) * lda + sg;
    const short* bp0 = Bt + (size_t)(bn + srow) * K   + sg;
    const short* bp1 = Bt + (size_t)(bn + 64 + srow) * K   + sg;
    const int lofs0 = wave * 512;
    const int lofs1 = 2048 + wave * 512;

    const int xr = (quad ^ ((l16 >> 1) & 3)) * 8;

#define STAGE_G(As, Bs, koff)                  \
    gload16(ap0 + (koff), (As) + lofs0);       \
    gload16(ap1 + (koff), (As) + lofs1);       \
    gload16(bp0 + (koff), (Bs) + lofs0);       \
    gload16(bp1 + (koff), (Bs) + lofs1);

#define COMPUTE_G(As, Bs)                                                   \
    {                                                                       \
        short8 a[4], b[4];                                                  \
        _Pragma("unroll")                                                   \
        for (int i = 0; i < 4; ++i)                                         \
            a[i] = *(const short8*)&(As)[(wr * 64 + i * 16 + l16) * 32 + xr]; \
        _Pragma("unroll")                                                   \
        for (int j = 0; j < 4; ++j)                                         \
            b[j] = *(const short8*)&(Bs)[(wc * 64 + j * 16 + l16) * 32 + xr]; \
        _Pragma("unroll")                                                   \
        for (int i = 0; i < 4; ++i)                                         \
            _Pragma("unroll")                                               \
            for (int j = 0; j < 4; ++j)                                     \
                acc[i][j] = mfma_bf16(a[i], b[j], acc[i][j]);               \
    }

    STAGE_G(A_s0, B_s0, 0);
    __syncthreads();

    for (int k0 = 0; k0 < K; k0 += 64) {
        if (k0 + 32 < K) { STAGE_G(A_s1, B_s1, k0 + 32); }
        COMPUTE_G(A_s0, B_s0);
        __syncthreads();
        if (k0 + 64 < K) { STAGE_G(A_s0, B_s0, k0 + 64); }
        COMPUTE_G(A_s1, B_s1);
        __syncthreads();
    }
#undef STAGE_G
#undef COMPUTE_G

    const float scale = (QSC && bn < 1024) ? QSCALE : 1.0f;
    #pragma unroll
    for (int i = 0; i < 4; ++i) {
        #pragma unroll
        for (int j = 0; j < 4; ++j) {
            #pragma unroll
            for (int r = 0; r < 4; ++r) {
                int row = bm + wr * 64 + i * 16 + quad * 4 + r;
                int col = bn + wc * 64 + j * 16 + l16;
                float v = acc[i][j][r] * scale;
                if (ADD_BIAS) v += bias[col];
                storeC(C, (size_t)row * N + col, v);
            }
        }
    }
}

// ---------------------------------------------------------------------------
// gemm64: BM=64, BN=128 variant of the same structure for the out-proj GEMM.
// Grid (8, 64) = 512 blocks -> 2 blocks/CU. 4 waves 2x2, per-wave 32x64.
// ---------------------------------------------------------------------------
template <bool ADD_BIAS, typename TC>
__global__ __launch_bounds__(256, 4) void gemm64(
    const short* __restrict__ A, const short* __restrict__ Bt,
    const float* __restrict__ bias, TC* __restrict__ C,
    int M, int N, int K, int lda)
{
    __shared__ short A_s0[64 * 32];
    __shared__ short A_s1[64 * 32];
    __shared__ short B_s0[128 * 32];
    __shared__ short B_s1[128 * 32];
    const int tid  = threadIdx.x;
    const int lane = tid & 63;
    const int wave = tid >> 6;
    const int quad = lane >> 4;
    const int l16  = lane & 15;
    const int wr   = wave >> 1;     // M half (32 rows)
    const int wc   = wave & 1;      // N half (64 cols)
    const int bm   = blockIdx.y * 64;
    const int bn   = blockIdx.x * 128;

    f32x4 acc[2][4];
    #pragma unroll
    for (int i = 0; i < 2; ++i)
        #pragma unroll
        for (int j = 0; j < 4; ++j)
            acc[i][j] = f32x4{0.f, 0.f, 0.f, 0.f};

    const int srow = tid >> 2;
    const int schk = tid & 3;
    const int sg   = (schk ^ ((srow >> 1) & 3)) * 8;
    const short* ap0 = A  + (size_t)(bm + srow) * lda + sg;
    const short* bp0 = Bt + (size_t)(bn + srow) * K   + sg;
    const short* bp1 = Bt + (size_t)(bn + 64 + srow) * K + sg;
    const int lofs0 = wave * 512;
    const int lofs1 = 2048 + wave * 512;

    const int xr = (quad ^ ((l16 >> 1) & 3)) * 8;

#define STAGE_H(As, Bs, koff)                  \
    gload16(ap0 + (koff), (As) + lofs0);       \
    gload16(bp0 + (koff), (Bs) + lofs0);       \
    gload16(bp1 + (koff), (Bs) + lofs1);

#define COMPUTE_H(As, Bs)                                                   \
    {                                                                       \
        short8 a[2], b[4];                                                  \
        _Pragma("unroll")                                                   \
        for (int i = 0; i < 2; ++i)                                         \
            a[i] = *(const short8*)&(As)[(wr * 32 + i * 16 + l16) * 32 + xr]; \
        _Pragma("unroll")                                                   \
        for (int j = 0; j < 4; ++j)                                         \
            b[j] = *(const short8*)&(Bs)[(wc * 64 + j * 16 + l16) * 32 + xr]; \
        _Pragma("unroll")                                                   \
        for (int i = 0; i < 2; ++i)                                         \
            _Pragma("unroll")                                               \
            for (int j = 0; j < 4; ++j)                                     \
                acc[i][j] = mfma_bf16(a[i], b[j], acc[i][j]);               \
    }

    STAGE_H(A_s0, B_s0, 0);
    __syncthreads();

    for (int k0 = 0; k0 < K; k0 += 64) {
        if (k0 + 32 < K) { STAGE_H(A_s1, B_s1, k0 + 32); }
        COMPUTE_H(A_s0, B_s0);
        __syncthreads();
        if (k0 + 64 < K) { STAGE_H(A_s0, B_s0, k0 + 64); }
        COMPUTE_H(A_s1, B_s1);
        __syncthreads();
    }
#undef STAGE_H
#undef COMPUTE_H

    #pragma unroll
    for (int i = 0; i < 2; ++i) {
        #pragma unroll
        for (int j = 0; j < 4; ++j) {
            #pragma unroll
            for (int r = 0; r < 4; ++r) {
                int row = bm + wr * 32 + i * 16 + quad * 4 + r;
                int col = bn + wc * 64 + j * 16 + l16;
                float v = acc[i][j][r];
                if (ADD_BIAS) v += bias[col];
                storeC(C, (size_t)row * N + col, v);
            }
        }
    }
}

// ---------------------------------------------------------------------------
// Flash attention v7 (round-6/8 version — best measured: 57.4-61.5 µs across
// 5 runs). Attn ledger: v8 q-split 64.6 (2x LDS traffic), v9 key-split 86.6
// (VGPR-64 spill), v9b key-split fixed 60.4 (lockstep waves stall together),
// v10 dbuf 67.6 (VGPR 160 / occupancy 10%). v7's 2-barrier reg-prefetch
// single-buffer is the local optimum: lowest VGPR (108), max q-amortization.
// 32 q-rows per wave; S^T MFMA -> exp2 -> direct K=16 PV; ctx in-place.
// grid (2048/128, 32) = 512 blocks.
// ---------------------------------------------------------------------------
__global__ __launch_bounds__(256) void attn128(
    short* __restrict__ qkv, const short* __restrict__ vt)
{
    __shared__ short Ks[128 * 72];   // [key][dim]
    __shared__ short Vs[16 * 520];   // [g][dim][k&7], g = key>>3 (tile-local)

    const int tid  = threadIdx.x;
    const int lane = tid & 63;
    const int wave = tid >> 6;
    const int quad = lane >> 4;
    const int l16  = lane & 15;
    const int bh   = blockIdx.y, b = bh >> 4, h = bh & 15;
    const int qb   = blockIdx.x * 128;
    const size_t rowbase = (size_t)b * 2048;

    // Q fragments for 2 q-groups (B-op for S^T), pre-scaled by log2e/32
    short8 aq[2][2];
    #pragma unroll
    for (int qg = 0; qg < 2; ++qg) {
        const short* qp = qkv + (rowbase + qb + wave * 32 + qg * 16 + l16) * 3072 + h * 64;
        aq[qg][0] = *(const short8*)(qp + quad * 8);
        aq[qg][1] = *(const short8*)(qp + 32 + quad * 8);
    }

    f32x4 o[2][4];
    #pragma unroll
    for (int qg = 0; qg < 2; ++qg)
        #pragma unroll
        for (int c = 0; c < 4; ++c) o[qg][c] = f32x4{0.f, 0.f, 0.f, 0.f};
    float rsum[2] = {0.f, 0.f};   // softmax denom partials for q = l16

    const int kkey = tid >> 1, kdc = (tid & 1) * 32;
    const int vdim = tid >> 2, vg0 = (tid & 3) * 4;
    const short* kbase = qkv + (rowbase + kkey) * 3072 + 1024 + h * 64 + kdc;
    const short* vbase = vt + ((size_t)bh * 64 + vdim) * 2048 + vg0 * 8;

    // prefetch tile 0
    short8 kr0 = *(const short8*)(kbase);
    short8 kr1 = *(const short8*)(kbase + 8);
    short8 kr2 = *(const short8*)(kbase + 16);
    short8 kr3 = *(const short8*)(kbase + 24);
    short8 vr0 = *(const short8*)(vbase);
    short8 vr1 = *(const short8*)(vbase + 8);
    short8 vr2 = *(const short8*)(vbase + 16);
    short8 vr3 = *(const short8*)(vbase + 24);

    for (int kt = 0; kt < 2048; kt += 128) {
        __syncthreads();                      // prior-tile LDS readers done
        *(short8*)&Ks[kkey * 72 + kdc]      = kr0;
        *(short8*)&Ks[kkey * 72 + kdc + 8]  = kr1;
        *(short8*)&Ks[kkey * 72 + kdc + 16] = kr2;
        *(short8*)&Ks[kkey * 72 + kdc + 24] = kr3;
        *(short8*)&Vs[(vg0 + 0) * 520 + vdim * 8] = vr0;
        *(short8*)&Vs[(vg0 + 1) * 520 + vdim * 8] = vr1;
        *(short8*)&Vs[(vg0 + 2) * 520 + vdim * 8] = vr2;
        *(short8*)&Vs[(vg0 + 3) * 520 + vdim * 8] = vr3;
        if (kt + 128 < 2048) {                // prefetch next tile
            const short* kp = kbase + (size_t)(kt + 128) * 3072;
            kr0 = *(const short8*)(kp);
            kr1 = *(const short8*)(kp + 8);
            kr2 = *(const short8*)(kp + 16);
            kr3 = *(const short8*)(kp + 24);
            const short* vp = vbase + kt + 128;
            vr0 = *(const short8*)(vp);
            vr1 = *(const short8*)(vp + 8);
            vr2 = *(const short8*)(vp + 16);
            vr3 = *(const short8*)(vp + 24);
        }
        __syncthreads();                      // tile visible

        // two chunks of 64 keys: S^T -> exp2 -> PV
        #pragma unroll
        for (int cc = 0; cc < 2; ++cc) {
            // S^T: lane holds S[q=l16][key=(cc*4+c4)*16+quad*4+r], per q-group
            f32x4 st[2][4];
            #pragma unroll
            for (int c4 = 0; c4 < 4; ++c4) {
                const int c = cc * 4 + c4;
                short8 ka0 = *(const short8*)&Ks[(c * 16 + l16) * 72 + quad * 8];
                short8 ka1 = *(const short8*)&Ks[(c * 16 + l16) * 72 + 32 + quad * 8];
                #pragma unroll
                for (int qg = 0; qg < 2; ++qg) {
                    f32x4 z = f32x4{0.f, 0.f, 0.f, 0.f};
                    z = mfma_bf16(ka0, aq[qg][0], z);
                    st[qg][c4] = mfma_bf16(ka1, aq[qg][1], z);
                }
            }
            // p = exp2(s'): bare v_exp_f32 + v_cvt_pk_bf16_f32 packing
            uint2v pa[2][4];
            #pragma unroll
            for (int qg = 0; qg < 2; ++qg) {
                #pragma unroll
                for (int c4 = 0; c4 < 4; ++c4) {
                    float p0 = fexp2(st[qg][c4][0]);
                    float p1 = fexp2(st[qg][c4][1]);
                    float p2 = fexp2(st[qg][c4][2]);
                    float p3 = fexp2(st[qg][c4][3]);
                    rsum[qg] += (p0 + p1) + (p2 + p3);
                    uint2v pk;
                    pk[0] = pkbf(p0, p1);
                    pk[1] = pkbf(p2, p3);
                    pa[qg][c4] = pk;
                }
            }
            // PV: bv read once, used by both q-groups
            #pragma unroll
            for (int c2 = 0; c2 < 4; ++c2) {
                #pragma unroll
                for (int c4 = 0; c4 < 4; ++c4) {
                    const int c = cc * 4 + c4;
                    uint2v bv = *(const uint2v*)&Vs[(2 * c + (quad >> 1)) * 520
                                                    + (c2 * 16 + l16) * 8
                                                    + (quad & 1) * 4];
                    #pragma unroll
                    for (int qg = 0; qg < 2; ++qg)
                        o[qg][c2] = mfma16(pa[qg][c4], bv, o[qg][c2]);
                }
            }
        }
    }

    // full denom for q=l16: sum over the 4 quad-lanes
    #pragma unroll
    for (int qg = 0; qg < 2; ++qg) {
        rsum[qg] += __shfl_xor(rsum[qg], 16, 64);
        rsum[qg] += __shfl_xor(rsum[qg], 32, 64);
    }

    // epilogue: o rows are q=quad*4+r; fetch that q's denom from lane q
    #pragma unroll
    for (int qg = 0; qg < 2; ++qg) {
        #pragma unroll
        for (int r = 0; r < 4; ++r) {
            float inv = 1.0f / __shfl(rsum[qg], quad * 4 + r, 64);
            size_t row = rowbase + qb + wave * 32 + qg * 16 + quad * 4 + r;
            #pragma unroll
            for (int c2 = 0; c2 < 4; ++c2)
                qkv[row * 3072 + h * 64 + c2 * 16 + l16] = f2b(o[qg][c2][r] * inv);
        }
    }
}

// ---------------------------------------------------------------------------
extern "C" void kernel_launch(void* const* d_in, const int* in_sizes, int n_in,
                              void* d_out, int out_size, void* d_ws, size_t ws_size,
                              hipStream_t stream)
{
    const float* x    = (const float*)d_in[0];   // (2,2048,1024) fp32
    const float* Wqkv = (const float*)d_in[2];   // (1024,3072) fp32
    const float* Wout = (const float*)d_in[3];   // (1024,1024) fp32
    const float* bout = (const float*)d_in[4];   // (1024,) fp32
    float* out = (float*)d_out;                  // (2,2048,1024) fp32

    // Buffer map:
    //   ws (32 MiB): qkv 24 MiB | wqkvt 6 MiB | woutt 2 MiB
    //   d_out (16 MiB): xbf lower 8 MiB (dead after gemm1)
    //                   vt  upper 8 MiB (dead after attn)
    //   gemm2 overwrites all of d_out last.
    short* qkv   = (short*)d_ws;                        // 4096 x 3072 bf16
    short* wqkvt = qkv + (size_t)4096 * 3072;           // 3072 x 1024 bf16
    short* woutt = wqkvt + (size_t)3072 * 1024;         // 1024 x 1024 bf16
    short* xbf   = (short*)d_out;                       // 4096 x 1024 bf16
    short* vtbuf = xbf + (size_t)4096 * 1024;           // 32 x 64 x 2048 bf16

    dim3 blk(256);
    prep<<<dim3(3072), blk, 0, stream>>>(x, xbf, Wqkv, wqkvt, Wout, woutt);
    gemm128<true, false, short><<<dim3(24, 32), blk, 0, stream>>>(
        xbf, wqkvt, nullptr, qkv, 4096, 3072, 1024, 1024);
    vtrans<<<dim3(32, 32), blk, 0, stream>>>(qkv, vtbuf);
    attn128<<<dim3(16, 32), blk, 0, stream>>>(qkv, vtbuf);
    gemm64<true, float><<<dim3(8, 64), blk, 0, stream>>>(
        qkv, woutt, bout, out, 4096, 1024, 1024, 3072);
}

// Round 14
// 187.513 us; speedup vs baseline: 1.0531x; 1.0199x over previous
//
#include <hip/hip_runtime.h>

typedef __attribute__((ext_vector_type(8))) short short8;
typedef __attribute__((ext_vector_type(4))) short s16x4;
typedef __attribute__((ext_vector_type(8))) __bf16 bf16x8;
typedef __attribute__((ext_vector_type(4))) __bf16 bf16x4;
typedef __attribute__((ext_vector_type(2))) __bf16 bf16x2;
typedef __attribute__((ext_vector_type(4))) float f32x4;
typedef __attribute__((ext_vector_type(2))) float f32x2;
typedef __attribute__((ext_vector_type(4))) unsigned uint4v;
typedef __attribute__((ext_vector_type(2))) unsigned uint2v;

__device__ inline f32x4 mfma_bf16(short8 a, short8 b, f32x4 c) {
    return __builtin_amdgcn_mfma_f32_16x16x32_bf16(
        __builtin_bit_cast(bf16x8, a), __builtin_bit_cast(bf16x8, b), c, 0, 0, 0);
}
// K=16 bf16 MFMA: A-frag layout A[m=l16][k=quad*4+j] == C/D layout of a prior
// MFMA transposed -> P needs no layout transform.
__device__ inline f32x4 mfma16(uint2v a, uint2v b, f32x4 c) {
#if __has_builtin(__builtin_amdgcn_mfma_f32_16x16x16_bf16)
    return __builtin_amdgcn_mfma_f32_16x16x16_bf16(
        __builtin_bit_cast(bf16x4, a), __builtin_bit_cast(bf16x4, b), c, 0, 0, 0);
#else
    return __builtin_amdgcn_mfma_f32_16x16x16bf16_1k(
        __builtin_bit_cast(s16x4, a), __builtin_bit_cast(s16x4, b), c, 0, 0, 0);
#endif
}

// fast exp2: bare v_exp_f32
__device__ inline float fexp2(float x) {
#if __has_builtin(__builtin_amdgcn_exp2f)
    return __builtin_amdgcn_exp2f(x);
#else
    return exp2f(x);
#endif
}

// fp32 -> bf16 via HW convert (v_cvt_pk_bf16_f32 on gfx950), RNE
__device__ inline short f2b(float f) {
    __bf16 h = (__bf16)f;
    return __builtin_bit_cast(short, h);
}
__device__ inline unsigned pkbf(float a, float b) {
    f32x2 v; v[0] = a; v[1] = b;
    bf16x2 h = __builtin_convertvector(v, bf16x2);
    return __builtin_bit_cast(unsigned, h);
}

__device__ inline short8 ld8(const short* p) { return *(const short8*)p; }
__device__ inline short8 ld8(const float* p) {
    f32x4 a = *(const f32x4*)p;
    f32x4 b = *(const f32x4*)(p + 4);
    uint4v q;
    q[0] = pkbf(a[0], a[1]); q[1] = pkbf(a[2], a[3]);
    q[2] = pkbf(b[0], b[1]); q[3] = pkbf(b[2], b[3]);
    return __builtin_bit_cast(short8, q);
}
__device__ inline void storeC(short* C, size_t i, float v) { C[i] = f2b(v); }
__device__ inline void storeC(float* C, size_t i, float v) { C[i] = v; }

// async global->LDS DMA, 16B per lane. LDS dest must be wave-uniform base;
// HW writes lane l at base + l*16 (m104/m108: no per-lane LDS scatter).
__device__ inline void gload16(const short* g, short* l) {
    __builtin_amdgcn_global_load_lds(
        (const __attribute__((address_space(1))) unsigned*)g,
        (__attribute__((address_space(3))) unsigned*)l, 16, 0, 0);
}

// log2(e)/32 : folded into Q so softmax uses exp2 (bare v_exp_f32)
#define QSCALE 0.04508422052265167f

// ---------------------------------------------------------------------------
// Fused prep: one launch does
//   blocks [0,2048):    x fp32 -> xbf bf16 bulk convert
//   blocks [2048,2816): Wqkv [1024][3072] -> wqkvt [3072][1024] bf16 k-major
//   blocks [2816,3072): Wout [1024][1024] -> woutt [1024][1024] bf16 k-major
// ---------------------------------------------------------------------------
__global__ __launch_bounds__(256) void prep(
    const float* __restrict__ x, short* __restrict__ xb,
    const float* __restrict__ Wqkv, short* __restrict__ wqkvt,
    const float* __restrict__ Wout, short* __restrict__ woutt)
{
    const int bid = blockIdx.x;
    const int tid = threadIdx.x;
    if (bid < 2048) {
        size_t i = ((size_t)bid * 256 + tid) * 8;
        *(short8*)(xb + i) = ld8(x + i);
        return;
    }
    __shared__ short T[64 * 72];
    const float* W; short* Wt; int K, N, n0, k0;
    if (bid < 2816) {
        const int b2 = bid - 2048;
        W = Wqkv; Wt = wqkvt; K = 1024; N = 3072;
        n0 = (b2 % 48) * 64; k0 = (b2 / 48) * 64;
    } else {
        const int b3 = bid - 2816;
        W = Wout; Wt = woutt; K = 1024; N = 1024;
        n0 = (b3 & 15) * 64; k0 = (b3 >> 4) * 64;
    }
    {
        const int kl = tid >> 2, nc = (tid & 3) * 16;
        const float* src = W + (size_t)(k0 + kl) * N + n0 + nc;
        float v[16];
        *(f32x4*)&v[0]  = *(const f32x4*)(src + 0);
        *(f32x4*)&v[4]  = *(const f32x4*)(src + 4);
        *(f32x4*)&v[8]  = *(const f32x4*)(src + 8);
        *(f32x4*)&v[12] = *(const f32x4*)(src + 12);
        #pragma unroll
        for (int j = 0; j < 16; ++j) T[(nc + j) * 72 + kl] = f2b(v[j]);
    }
    __syncthreads();
    {
        const int nl = tid >> 2, kc = (tid & 3) * 16;
        short8 w0 = *(const short8*)&T[nl * 72 + kc];
        short8 w1 = *(const short8*)&T[nl * 72 + kc + 8];
        short* dst = Wt + (size_t)(n0 + nl) * K + k0 + kc;
        *(short8*)dst = w0;
        *(short8*)(dst + 8) = w1;
    }
}

// ---------------------------------------------------------------------------
// GEMM: global_load_lds DMA staging + double-buffered LDS 2-phase pipeline.
// C = A @ Bt^T (+bias). 128x128 tile, BK=32, 4 waves 2x2 (64x64 each).
// STAGE(next) issued BEFORE COMPUTE(cur); one barrier per K-step.
// Bank-swizzle: source chunk c ^ ((row>>1)&3), read slot quad ^ ((l16>>1)&3).
// QSC: scale cols<1024 by log2(e)/32 (Q pre-scale for exp2 softmax).
//
// FUSED V-TRANSPOSE: for blocks with bn >= vstart (the V panel of the qkv
// projection), the epilogue writes vt[(b*16+h)*64+dim][tok] instead of C —
// eliminating the separate vtrans kernel and its 16 MB HBM round-trip. The
// 4 dead LDS tile buffers (32 KB = exactly a 128x128 bf16 tile) are reused:
//   stage:  SM[col*128 + (G^gc)*4 ..] <- acc (4-short granules, G=tok>>2,
//           gc=col&31; granule-XOR -> 4-way banks on write AND read)
//   read:   thread t owns (col=t>>1, 64 toks); assembles short8, stores
//           coalesced-in-tok to vt. Value path f2b(acc) identical to the
//           old qkv->vtrans path -> bit-identical output.
// qkv's V region is no longer written (only vtrans consumed it).
// ---------------------------------------------------------------------------
template <bool QSC, typename TC>
__global__ __launch_bounds__(256, 4) void gemm128(
    const short* __restrict__ A, const short* __restrict__ Bt,
    TC* __restrict__ C, short* __restrict__ vtout, int vstart,
    int M, int N, int K, int lda)
{
    __shared__ short SM[128 * 128];       // 4 x (128*32) tile buffers, merged
    short* const A_s0 = SM;
    short* const A_s1 = SM + 4096;
    short* const B_s0 = SM + 8192;
    short* const B_s1 = SM + 12288;
    const int tid  = threadIdx.x;
    const int lane = tid & 63;
    const int wave = tid >> 6;
    const int quad = lane >> 4;
    const int l16  = lane & 15;
    const int wr   = wave >> 1;
    const int wc   = wave & 1;
    const int bm   = blockIdx.y * 128;
    const int bn   = blockIdx.x * 128;

    f32x4 acc[4][4];
    #pragma unroll
    for (int i = 0; i < 4; ++i)
        #pragma unroll
        for (int j = 0; j < 4; ++j)
            acc[i][j] = f32x4{0.f, 0.f, 0.f, 0.f};

    const int srow = tid >> 2;
    const int schk = tid & 3;
    const int sg   = (schk ^ ((srow >> 1) & 3)) * 8;
    const short* ap0 = A  + (size_t)(bm + srow) * lda + sg;
    const short* ap1 = A  + (size_t)(bm + 64 + srow) * lda + sg;
    const short* bp0 = Bt + (size_t)(bn + srow) * K   + sg;
    const short* bp1 = Bt + (size_t)(bn + 64 + srow) * K   + sg;
    const int lofs0 = wave * 512;
    const int lofs1 = 2048 + wave * 512;

    const int xr = (quad ^ ((l16 >> 1) & 3)) * 8;

#define STAGE_G(As, Bs, koff)                  \
    gload16(ap0 + (koff), (As) + lofs0);       \
    gload16(ap1 + (koff), (As) + lofs1);       \
    gload16(bp0 + (koff), (Bs) + lofs0);       \
    gload16(bp1 + (koff), (Bs) + lofs1);

#define COMPUTE_G(As, Bs)                                                   \
    {                                                                       \
        short8 a[4], b[4];                                                  \
        _Pragma("unroll")                                                   \
        for (int i = 0; i < 4; ++i)                                         \
            a[i] = *(const short8*)&(As)[(wr * 64 + i * 16 + l16) * 32 + xr]; \
        _Pragma("unroll")                                                   \
        for (int j = 0; j < 4; ++j)                                         \
            b[j] = *(const short8*)&(Bs)[(wc * 64 + j * 16 + l16) * 32 + xr]; \
        _Pragma("unroll")                                                   \
        for (int i = 0; i < 4; ++i)                                         \
            _Pragma("unroll")                                               \
            for (int j = 0; j < 4; ++j)                                     \
                acc[i][j] = mfma_bf16(a[i], b[j], acc[i][j]);               \
    }

    STAGE_G(A_s0, B_s0, 0);
    __syncthreads();

    for (int k0 = 0; k0 < K; k0 += 64) {
        if (k0 + 32 < K) { STAGE_G(A_s1, B_s1, k0 + 32); }
        COMPUTE_G(A_s0, B_s0);
        __syncthreads();
        if (k0 + 64 < K) { STAGE_G(A_s0, B_s0, k0 + 64); }
        COMPUTE_G(A_s1, B_s1);
        __syncthreads();
    }
#undef STAGE_G
#undef COMPUTE_G

    if (vtout != nullptr && bn >= vstart) {
        // ---- fused V-transpose epilogue (block-uniform branch) ----
        // stage acc into SM[col][tok] with granule-XOR swizzle
        #pragma unroll
        for (int i = 0; i < 4; ++i) {
            #pragma unroll
            for (int j = 0; j < 4; ++j) {
                const int col  = wc * 64 + j * 16 + l16;
                const int tok0 = wr * 64 + i * 16 + quad * 4;
                const int G    = (tok0 >> 2) ^ (col & 31);
                s16x4 v4;
                #pragma unroll
                for (int r = 0; r < 4; ++r) v4[r] = f2b(acc[i][j][r]);
                *(s16x4*)&SM[col * 128 + G * 4] = v4;
            }
        }
        __syncthreads();
        // write out: thread t owns (col=t>>1, toks (t&1)*64 .. +63)
        {
            const int col2  = tid >> 1;
            const int gc    = col2 & 31;
            const int gbase = (tid & 1) * 16;          // granule base (4 toks each)
            const short* base = SM + col2 * 128;
            const int gcol = bn + col2 - 2048;         // V panel col
            const int hh   = gcol >> 6, dim = gcol & 63;
            const int bb   = bm >> 11;                 // batch (tiles don't straddle)
            short* dst = vtout + ((size_t)(bb * 16 + hh) * 64 + dim) * 2048
                               + (bm & 2047) + gbase * 4;
            #pragma unroll
            for (int u = 0; u < 16; u += 2) {
                s16x4 a = *(const s16x4*)&base[((gbase + u)     ^ gc) * 4];
                s16x4 b = *(const s16x4*)&base[((gbase + u + 1) ^ gc) * 4];
                short8 w;
                w[0] = a[0]; w[1] = a[1]; w[2] = a[2]; w[3] = a[3];
                w[4] = b[0]; w[5] = b[1]; w[6] = b[2]; w[7] = b[3];
                *(short8*)(dst + u * 4) = w;
            }
        }
        return;
    }

    const float scale = (QSC && bn < 1024) ? QSCALE : 1.0f;
    #pragma unroll
    for (int i = 0; i < 4; ++i) {
        #pragma unroll
        for (int j = 0; j < 4; ++j) {
            #pragma unroll
            for (int r = 0; r < 4; ++r) {
                int row = bm + wr * 64 + i * 16 + quad * 4 + r;
                int col = bn + wc * 64 + j * 16 + l16;
                float v = acc[i][j][r] * scale;
                storeC(C, (size_t)row * N + col, v);
            }
        }
    }
}

// ---------------------------------------------------------------------------
// gemm64: BM=64, BN=128 variant of the same structure for the out-proj GEMM.
// Grid (8, 64) = 512 blocks -> 2 blocks/CU. 4 waves 2x2, per-wave 32x64.
// ---------------------------------------------------------------------------
template <bool ADD_BIAS, typename TC>
__global__ __launch_bounds__(256, 4) void gemm64(
    const short* __restrict__ A, const short* __restrict__ Bt,
    const float* __restrict__ bias, TC* __restrict__ C,
    int M, int N, int K, int lda)
{
    __shared__ short A_s0[64 * 32];
    __shared__ short A_s1[64 * 32];
    __shared__ short B_s0[128 * 32];
    __shared__ short B_s1[128 * 32];
    const int tid  = threadIdx.x;
    const int lane = tid & 63;
    const int wave = tid >> 6;
    const int quad = lane >> 4;
    const int l16  = lane & 15;
    const int wr   = wave >> 1;     // M half (32 rows)
    const int wc   = wave & 1;      // N half (64 cols)
    const int bm   = blockIdx.y * 64;
    const int bn   = blockIdx.x * 128;

    f32x4 acc[2][4];
    #pragma unroll
    for (int i = 0; i < 2; ++i)
        #pragma unroll
        for (int j = 0; j < 4; ++j)
            acc[i][j] = f32x4{0.f, 0.f, 0.f, 0.f};

    const int srow = tid >> 2;
    const int schk = tid & 3;
    const int sg   = (schk ^ ((srow >> 1) & 3)) * 8;
    const short* ap0 = A  + (size_t)(bm + srow) * lda + sg;
    const short* bp0 = Bt + (size_t)(bn + srow) * K   + sg;
    const short* bp1 = Bt + (size_t)(bn + 64 + srow) * K + sg;
    const int lofs0 = wave * 512;
    const int lofs1 = 2048 + wave * 512;

    const int xr = (quad ^ ((l16 >> 1) & 3)) * 8;

#define STAGE_H(As, Bs, koff)                  \
    gload16(ap0 + (koff), (As) + lofs0);       \
    gload16(bp0 + (koff), (Bs) + lofs0);       \
    gload16(bp1 + (koff), (Bs) + lofs1);

#define COMPUTE_H(As, Bs)                                                   \
    {                                                                       \
        short8 a[2], b[4];                                                  \
        _Pragma("unroll")                                                   \
        for (int i = 0; i < 2; ++i)                                         \
            a[i] = *(const short8*)&(As)[(wr * 32 + i * 16 + l16) * 32 + xr]; \
        _Pragma("unroll")                                                   \
        for (int j = 0; j < 4; ++j)                                         \
            b[j] = *(const short8*)&(Bs)[(wc * 64 + j * 16 + l16) * 32 + xr]; \
        _Pragma("unroll")                                                   \
        for (int i = 0; i < 2; ++i)                                         \
            _Pragma("unroll")                                               \
            for (int j = 0; j < 4; ++j)                                     \
                acc[i][j] = mfma_bf16(a[i], b[j], acc[i][j]);               \
    }

    STAGE_H(A_s0, B_s0, 0);
    __syncthreads();

    for (int k0 = 0; k0 < K; k0 += 64) {
        if (k0 + 32 < K) { STAGE_H(A_s1, B_s1, k0 + 32); }
        COMPUTE_H(A_s0, B_s0);
        __syncthreads();
        if (k0 + 64 < K) { STAGE_H(A_s0, B_s0, k0 + 64); }
        COMPUTE_H(A_s1, B_s1);
        __syncthreads();
    }
#undef STAGE_H
#undef COMPUTE_H

    #pragma unroll
    for (int i = 0; i < 2; ++i) {
        #pragma unroll
        for (int j = 0; j < 4; ++j) {
            #pragma unroll
            for (int r = 0; r < 4; ++r) {
                int row = bm + wr * 32 + i * 16 + quad * 4 + r;
                int col = bn + wc * 64 + j * 16 + l16;
                float v = acc[i][j][r];
                if (ADD_BIAS) v += bias[col];
                storeC(C, (size_t)row * N + col, v);
            }
        }
    }
}

// ---------------------------------------------------------------------------
// Flash attention v7 (best measured: 57.2-61.5 µs across 6 runs). Ledger:
// v8 q-split 64.6 (2x LDS traffic), v9 key-split 86.6 (spill), v9b 60.4
// (lockstep waves stall together), v10 dbuf 67.6 (VGPR 160 / occ 10%).
// v7's 2-barrier reg-prefetch single-buffer is the local optimum.
// 32 q-rows per wave; S^T MFMA -> exp2 -> direct K=16 PV; ctx in-place.
// grid (2048/128, 32) = 512 blocks.
// ---------------------------------------------------------------------------
__global__ __launch_bounds__(256) void attn128(
    short* __restrict__ qkv, const short* __restrict__ vt)
{
    __shared__ short Ks[128 * 72];   // [key][dim]
    __shared__ short Vs[16 * 520];   // [g][dim][k&7], g = key>>3 (tile-local)

    const int tid  = threadIdx.x;
    const int lane = tid & 63;
    const int wave = tid >> 6;
    const int quad = lane >> 4;
    const int l16  = lane & 15;
    const int bh   = blockIdx.y, b = bh >> 4, h = bh & 15;
    const int qb   = blockIdx.x * 128;
    const size_t rowbase = (size_t)b * 2048;

    // Q fragments for 2 q-groups (B-op for S^T), pre-scaled by log2e/32
    short8 aq[2][2];
    #pragma unroll
    for (int qg = 0; qg < 2; ++qg) {
        const short* qp = qkv + (rowbase + qb + wave * 32 + qg * 16 + l16) * 3072 + h * 64;
        aq[qg][0] = *(const short8*)(qp + quad * 8);
        aq[qg][1] = *(const short8*)(qp + 32 + quad * 8);
    }

    f32x4 o[2][4];
    #pragma unroll
    for (int qg = 0; qg < 2; ++qg)
        #pragma unroll
        for (int c = 0; c < 4; ++c) o[qg][c] = f32x4{0.f, 0.f, 0.f, 0.f};
    float rsum[2] = {0.f, 0.f};   // softmax denom partials for q = l16

    const int kkey = tid >> 1, kdc = (tid & 1) * 32;
    const int vdim = tid >> 2, vg0 = (tid & 3) * 4;
    const short* kbase = qkv + (rowbase + kkey) * 3072 + 1024 + h * 64 + kdc;
    const short* vbase = vt + ((size_t)bh * 64 + vdim) * 2048 + vg0 * 8;

    // prefetch tile 0
    short8 kr0 = *(const short8*)(kbase);
    short8 kr1 = *(const short8*)(kbase + 8);
    short8 kr2 = *(const short8*)(kbase + 16);
    short8 kr3 = *(const short8*)(kbase + 24);
    short8 vr0 = *(const short8*)(vbase);
    short8 vr1 = *(const short8*)(vbase + 8);
    short8 vr2 = *(const short8*)(vbase + 16);
    short8 vr3 = *(const short8*)(vbase + 24);

    for (int kt = 0; kt < 2048; kt += 128) {
        __syncthreads();                      // prior-tile LDS readers done
        *(short8*)&Ks[kkey * 72 + kdc]      = kr0;
        *(short8*)&Ks[kkey * 72 + kdc + 8]  = kr1;
        *(short8*)&Ks[kkey * 72 + kdc + 16] = kr2;
        *(short8*)&Ks[kkey * 72 + kdc + 24] = kr3;
        *(short8*)&Vs[(vg0 + 0) * 520 + vdim * 8] = vr0;
        *(short8*)&Vs[(vg0 + 1) * 520 + vdim * 8] = vr1;
        *(short8*)&Vs[(vg0 + 2) * 520 + vdim * 8] = vr2;
        *(short8*)&Vs[(vg0 + 3) * 520 + vdim * 8] = vr3;
        if (kt + 128 < 2048) {                // prefetch next tile
            const short* kp = kbase + (size_t)(kt + 128) * 3072;
            kr0 = *(const short8*)(kp);
            kr1 = *(const short8*)(kp + 8);
            kr2 = *(const short8*)(kp + 16);
            kr3 = *(const short8*)(kp + 24);
            const short* vp = vbase + kt + 128;
            vr0 = *(const short8*)(vp);
            vr1 = *(const short8*)(vp + 8);
            vr2 = *(const short8*)(vp + 16);
            vr3 = *(const short8*)(vp + 24);
        }
        __syncthreads();                      // tile visible

        // two chunks of 64 keys: S^T -> exp2 -> PV
        #pragma unroll
        for (int cc = 0; cc < 2; ++cc) {
            // S^T: lane holds S[q=l16][key=(cc*4+c4)*16+quad*4+r], per q-group
            f32x4 st[2][4];
            #pragma unroll
            for (int c4 = 0; c4 < 4; ++c4) {
                const int c = cc * 4 + c4;
                short8 ka0 = *(const short8*)&Ks[(c * 16 + l16) * 72 + quad * 8];
                short8 ka1 = *(const short8*)&Ks[(c * 16 + l16) * 72 + 32 + quad * 8];
                #pragma unroll
                for (int qg = 0; qg < 2; ++qg) {
                    f32x4 z = f32x4{0.f, 0.f, 0.f, 0.f};
                    z = mfma_bf16(ka0, aq[qg][0], z);
                    st[qg][c4] = mfma_bf16(ka1, aq[qg][1], z);
                }
            }
            // p = exp2(s'): bare v_exp_f32 + v_cvt_pk_bf16_f32 packing
            uint2v pa[2][4];
            #pragma unroll
            for (int qg = 0; qg < 2; ++qg) {
                #pragma unroll
                for (int c4 = 0; c4 < 4; ++c4) {
                    float p0 = fexp2(st[qg][c4][0]);
                    float p1 = fexp2(st[qg][c4][1]);
                    float p2 = fexp2(st[qg][c4][2]);
                    float p3 = fexp2(st[qg][c4][3]);
                    rsum[qg] += (p0 + p1) + (p2 + p3);
                    uint2v pk;
                    pk[0] = pkbf(p0, p1);
                    pk[1] = pkbf(p2, p3);
                    pa[qg][c4] = pk;
                }
            }
            // PV: bv read once, used by both q-groups
            #pragma unroll
            for (int c2 = 0; c2 < 4; ++c2) {
                #pragma unroll
                for (int c4 = 0; c4 < 4; ++c4) {
                    const int c = cc * 4 + c4;
                    uint2v bv = *(const uint2v*)&Vs[(2 * c + (quad >> 1)) * 520
                                                    + (c2 * 16 + l16) * 8
                                                    + (quad & 1) * 4];
                    #pragma unroll
                    for (int qg = 0; qg < 2; ++qg)
                        o[qg][c2] = mfma16(pa[qg][c4], bv, o[qg][c2]);
                }
            }
        }
    }

    // full denom for q=l16: sum over the 4 quad-lanes
    #pragma unroll
    for (int qg = 0; qg < 2; ++qg) {
        rsum[qg] += __shfl_xor(rsum[qg], 16, 64);
        rsum[qg] += __shfl_xor(rsum[qg], 32, 64);
    }

    // epilogue: o rows are q=quad*4+r; fetch that q's denom from lane q
    #pragma unroll
    for (int qg = 0; qg < 2; ++qg) {
        #pragma unroll
        for (int r = 0; r < 4; ++r) {
            float inv = 1.0f / __shfl(rsum[qg], quad * 4 + r, 64);
            size_t row = rowbase + qb + wave * 32 + qg * 16 + quad * 4 + r;
            #pragma unroll
            for (int c2 = 0; c2 < 4; ++c2)
                qkv[row * 3072 + h * 64 + c2 * 16 + l16] = f2b(o[qg][c2][r] * inv);
        }
    }
}

// ---------------------------------------------------------------------------
extern "C" void kernel_launch(void* const* d_in, const int* in_sizes, int n_in,
                              void* d_out, int out_size, void* d_ws, size_t ws_size,
                              hipStream_t stream)
{
    const float* x    = (const float*)d_in[0];   // (2,2048,1024) fp32
    const float* Wqkv = (const float*)d_in[2];   // (1024,3072) fp32
    const float* Wout = (const float*)d_in[3];   // (1024,1024) fp32
    const float* bout = (const float*)d_in[4];   // (1024,) fp32
    float* out = (float*)d_out;                  // (2,2048,1024) fp32

    // Buffer map:
    //   ws (32 MiB): qkv 24 MiB | wqkvt 6 MiB | woutt 2 MiB
    //   d_out (16 MiB): xbf lower 8 MiB (dead after gemm1)
    //                   vt  upper 8 MiB (written by gemm1's fused epilogue,
    //                                    dead after attn)
    //   gemm2 overwrites all of d_out last.
    short* qkv   = (short*)d_ws;                        // 4096 x 3072 bf16
    short* wqkvt = qkv + (size_t)4096 * 3072;           // 3072 x 1024 bf16
    short* woutt = wqkvt + (size_t)3072 * 1024;         // 1024 x 1024 bf16
    short* xbf   = (short*)d_out;                       // 4096 x 1024 bf16
    short* vtbuf = xbf + (size_t)4096 * 1024;           // 32 x 64 x 2048 bf16

    dim3 blk(256);
    prep<<<dim3(3072), blk, 0, stream>>>(x, xbf, Wqkv, wqkvt, Wout, woutt);
    gemm128<true, short><<<dim3(24, 32), blk, 0, stream>>>(
        xbf, wqkvt, qkv, vtbuf, 2048, 4096, 3072, 1024, 1024);
    attn128<<<dim3(16, 32), blk, 0, stream>>>(qkv, vtbuf);
    gemm64<true, float><<<dim3(8, 64), blk, 0, stream>>>(
        qkv, woutt, bout, out, 4096, 1024, 1024, 3072);
}

// Round 15
// 185.667 us; speedup vs baseline: 1.0636x; 1.0099x over previous
//
#include <hip/hip_runtime.h>

typedef __attribute__((ext_vector_type(8))) short short8;
typedef __attribute__((ext_vector_type(4))) short s16x4;
typedef __attribute__((ext_vector_type(8))) __bf16 bf16x8;
typedef __attribute__((ext_vector_type(4))) __bf16 bf16x4;
typedef __attribute__((ext_vector_type(2))) __bf16 bf16x2;
typedef __attribute__((ext_vector_type(4))) float f32x4;
typedef __attribute__((ext_vector_type(2))) float f32x2;
typedef __attribute__((ext_vector_type(4))) unsigned uint4v;
typedef __attribute__((ext_vector_type(2))) unsigned uint2v;

__device__ inline f32x4 mfma_bf16(short8 a, short8 b, f32x4 c) {
    return __builtin_amdgcn_mfma_f32_16x16x32_bf16(
        __builtin_bit_cast(bf16x8, a), __builtin_bit_cast(bf16x8, b), c, 0, 0, 0);
}
// K=16 bf16 MFMA: A-frag layout A[m=l16][k=quad*4+j] == C/D layout of a prior
// MFMA transposed -> P needs no layout transform.
__device__ inline f32x4 mfma16(uint2v a, uint2v b, f32x4 c) {
#if __has_builtin(__builtin_amdgcn_mfma_f32_16x16x16_bf16)
    return __builtin_amdgcn_mfma_f32_16x16x16_bf16(
        __builtin_bit_cast(bf16x4, a), __builtin_bit_cast(bf16x4, b), c, 0, 0, 0);
#else
    return __builtin_amdgcn_mfma_f32_16x16x16bf16_1k(
        __builtin_bit_cast(s16x4, a), __builtin_bit_cast(s16x4, b), c, 0, 0, 0);
#endif
}

// fast exp2: bare v_exp_f32
__device__ inline float fexp2(float x) {
#if __has_builtin(__builtin_amdgcn_exp2f)
    return __builtin_amdgcn_exp2f(x);
#else
    return exp2f(x);
#endif
}

// fp32 -> bf16 via HW convert (v_cvt_pk_bf16_f32 on gfx950), RNE
__device__ inline short f2b(float f) {
    __bf16 h = (__bf16)f;
    return __builtin_bit_cast(short, h);
}
__device__ inline unsigned pkbf(float a, float b) {
    f32x2 v; v[0] = a; v[1] = b;
    bf16x2 h = __builtin_convertvector(v, bf16x2);
    return __builtin_bit_cast(unsigned, h);
}

__device__ inline short8 ld8(const short* p) { return *(const short8*)p; }
__device__ inline short8 ld8(const float* p) {
    f32x4 a = *(const f32x4*)p;
    f32x4 b = *(const f32x4*)(p + 4);
    uint4v q;
    q[0] = pkbf(a[0], a[1]); q[1] = pkbf(a[2], a[3]);
    q[2] = pkbf(b[0], b[1]); q[3] = pkbf(b[2], b[3]);
    return __builtin_bit_cast(short8, q);
}
__device__ inline void storeC(short* C, size_t i, float v) { C[i] = f2b(v); }
__device__ inline void storeC(float* C, size_t i, float v) { C[i] = v; }

// async global->LDS DMA, 16B per lane. LDS dest must be wave-uniform base;
// HW writes lane l at base + l*16 (m104/m108: no per-lane LDS scatter).
__device__ inline void gload16(const short* g, short* l) {
    __builtin_amdgcn_global_load_lds(
        (const __attribute__((address_space(1))) unsigned*)g,
        (__attribute__((address_space(3))) unsigned*)l, 16, 0, 0);
}

// log2(e)/32 : folded into Q so softmax uses exp2 (bare v_exp_f32)
#define QSCALE 0.04508422052265167f

// ---------------------------------------------------------------------------
// Fused prep: one launch does
//   blocks [0,2048):    x fp32 -> xbf bf16 bulk convert
//   blocks [2048,2816): Wqkv [1024][3072] -> wqkvt [3072][1024] bf16 k-major
//   blocks [2816,3072): Wout [1024][1024] -> woutt [1024][1024] bf16 k-major
// ---------------------------------------------------------------------------
__global__ __launch_bounds__(256) void prep(
    const float* __restrict__ x, short* __restrict__ xb,
    const float* __restrict__ Wqkv, short* __restrict__ wqkvt,
    const float* __restrict__ Wout, short* __restrict__ woutt)
{
    const int bid = blockIdx.x;
    const int tid = threadIdx.x;
    if (bid < 2048) {
        size_t i = ((size_t)bid * 256 + tid) * 8;
        *(short8*)(xb + i) = ld8(x + i);
        return;
    }
    __shared__ short T[64 * 72];
    const float* W; short* Wt; int K, N, n0, k0;
    if (bid < 2816) {
        const int b2 = bid - 2048;
        W = Wqkv; Wt = wqkvt; K = 1024; N = 3072;
        n0 = (b2 % 48) * 64; k0 = (b2 / 48) * 64;
    } else {
        const int b3 = bid - 2816;
        W = Wout; Wt = woutt; K = 1024; N = 1024;
        n0 = (b3 & 15) * 64; k0 = (b3 >> 4) * 64;
    }
    {
        const int kl = tid >> 2, nc = (tid & 3) * 16;
        const float* src = W + (size_t)(k0 + kl) * N + n0 + nc;
        float v[16];
        *(f32x4*)&v[0]  = *(const f32x4*)(src + 0);
        *(f32x4*)&v[4]  = *(const f32x4*)(src + 4);
        *(f32x4*)&v[8]  = *(const f32x4*)(src + 8);
        *(f32x4*)&v[12] = *(const f32x4*)(src + 12);
        #pragma unroll
        for (int j = 0; j < 16; ++j) T[(nc + j) * 72 + kl] = f2b(v[j]);
    }
    __syncthreads();
    {
        const int nl = tid >> 2, kc = (tid & 3) * 16;
        short8 w0 = *(const short8*)&T[nl * 72 + kc];
        short8 w1 = *(const short8*)&T[nl * 72 + kc + 8];
        short* dst = Wt + (size_t)(n0 + nl) * K + k0 + kc;
        *(short8*)dst = w0;
        *(short8*)(dst + 8) = w1;
    }
}

// ---------------------------------------------------------------------------
// GEMM: global_load_lds DMA staging + double-buffered LDS 2-phase pipeline.
// C = A @ Bt^T (+bias). 128x128 tile, BK=32, 4 waves 2x2 (64x64 each).
// STAGE(next) issued BEFORE COMPUTE(cur); one barrier per K-step.
// Bank-swizzle: source chunk c ^ ((row>>1)&3), read slot quad ^ ((l16>>1)&3).
// QSC: scale cols<1024 by log2(e)/32 (Q pre-scale for exp2 softmax).
//
// FUSED V-TRANSPOSE: for blocks with bn >= vstart (the V panel of the qkv
// projection), the epilogue writes vt[(b*16+h)*64+dim][tok] instead of C —
// eliminating the separate vtrans kernel and its 16 MB HBM round-trip. The
// 4 dead LDS tile buffers (32 KB = exactly a 128x128 bf16 tile) are reused:
//   stage:  SM[col*128 + (G^gc)*4 ..] <- acc (4-short granules, G=tok>>2,
//           gc=col&31; granule-XOR -> 4-way banks on write AND read)
//   read:   thread t owns (col=t>>1, 64 toks); assembles short8, stores
//           coalesced-in-tok to vt. Value path f2b(acc) identical to the
//           old qkv->vtrans path -> bit-identical output.
// qkv's V region is no longer written (only vtrans consumed it).
// ---------------------------------------------------------------------------
template <bool QSC, typename TC>
__global__ __launch_bounds__(256, 4) void gemm128(
    const short* __restrict__ A, const short* __restrict__ Bt,
    TC* __restrict__ C, short* __restrict__ vtout, int vstart,
    int M, int N, int K, int lda)
{
    __shared__ short SM[128 * 128];       // 4 x (128*32) tile buffers, merged
    short* const A_s0 = SM;
    short* const A_s1 = SM + 4096;
    short* const B_s0 = SM + 8192;
    short* const B_s1 = SM + 12288;
    const int tid  = threadIdx.x;
    const int lane = tid & 63;
    const int wave = tid >> 6;
    const int quad = lane >> 4;
    const int l16  = lane & 15;
    const int wr   = wave >> 1;
    const int wc   = wave & 1;
    const int bm   = blockIdx.y * 128;
    const int bn   = blockIdx.x * 128;

    f32x4 acc[4][4];
    #pragma unroll
    for (int i = 0; i < 4; ++i)
        #pragma unroll
        for (int j = 0; j < 4; ++j)
            acc[i][j] = f32x4{0.f, 0.f, 0.f, 0.f};

    const int srow = tid >> 2;
    const int schk = tid & 3;
    const int sg   = (schk ^ ((srow >> 1) & 3)) * 8;
    const short* ap0 = A  + (size_t)(bm + srow) * lda + sg;
    const short* ap1 = A  + (size_t)(bm + 64 + srow) * lda + sg;
    const short* bp0 = Bt + (size_t)(bn + srow) * K   + sg;
    const short* bp1 = Bt + (size_t)(bn + 64 + srow) * K   + sg;
    const int lofs0 = wave * 512;
    const int lofs1 = 2048 + wave * 512;

    const int xr = (quad ^ ((l16 >> 1) & 3)) * 8;

#define STAGE_G(As, Bs, koff)                  \
    gload16(ap0 + (koff), (As) + lofs0);       \
    gload16(ap1 + (koff), (As) + lofs1);       \
    gload16(bp0 + (koff), (Bs) + lofs0);       \
    gload16(bp1 + (koff), (Bs) + lofs1);

#define COMPUTE_G(As, Bs)                                                   \
    {                                                                       \
        short8 a[4], b[4];                                                  \
        _Pragma("unroll")                                                   \
        for (int i = 0; i < 4; ++i)                                         \
            a[i] = *(const short8*)&(As)[(wr * 64 + i * 16 + l16) * 32 + xr]; \
        _Pragma("unroll")                                                   \
        for (int j = 0; j < 4; ++j)                                         \
            b[j] = *(const short8*)&(Bs)[(wc * 64 + j * 16 + l16) * 32 + xr]; \
        _Pragma("unroll")                                                   \
        for (int i = 0; i < 4; ++i)                                         \
            _Pragma("unroll")                                               \
            for (int j = 0; j < 4; ++j)                                     \
                acc[i][j] = mfma_bf16(a[i], b[j], acc[i][j]);               \
    }

    STAGE_G(A_s0, B_s0, 0);
    __syncthreads();

    for (int k0 = 0; k0 < K; k0 += 64) {
        if (k0 + 32 < K) { STAGE_G(A_s1, B_s1, k0 + 32); }
        COMPUTE_G(A_s0, B_s0);
        __syncthreads();
        if (k0 + 64 < K) { STAGE_G(A_s0, B_s0, k0 + 64); }
        COMPUTE_G(A_s1, B_s1);
        __syncthreads();
    }
#undef STAGE_G
#undef COMPUTE_G

    if (vtout != nullptr && bn >= vstart) {
        // ---- fused V-transpose epilogue (block-uniform branch) ----
        // stage acc into SM[col][tok] with granule-XOR swizzle
        #pragma unroll
        for (int i = 0; i < 4; ++i) {
            #pragma unroll
            for (int j = 0; j < 4; ++j) {
                const int col  = wc * 64 + j * 16 + l16;
                const int tok0 = wr * 64 + i * 16 + quad * 4;
                const int G    = (tok0 >> 2) ^ (col & 31);
                s16x4 v4;
                #pragma unroll
                for (int r = 0; r < 4; ++r) v4[r] = f2b(acc[i][j][r]);
                *(s16x4*)&SM[col * 128 + G * 4] = v4;
            }
        }
        __syncthreads();
        // write out: thread t owns (col=t>>1, toks (t&1)*64 .. +63)
        {
            const int col2  = tid >> 1;
            const int gc    = col2 & 31;
            const int gbase = (tid & 1) * 16;          // granule base (4 toks each)
            const short* base = SM + col2 * 128;
            const int gcol = bn + col2 - 2048;         // V panel col
            const int hh   = gcol >> 6, dim = gcol & 63;
            const int bb   = bm >> 11;                 // batch (tiles don't straddle)
            short* dst = vtout + ((size_t)(bb * 16 + hh) * 64 + dim) * 2048
                               + (bm & 2047) + gbase * 4;
            #pragma unroll
            for (int u = 0; u < 16; u += 2) {
                s16x4 a = *(const s16x4*)&base[((gbase + u)     ^ gc) * 4];
                s16x4 b = *(const s16x4*)&base[((gbase + u + 1) ^ gc) * 4];
                short8 w;
                w[0] = a[0]; w[1] = a[1]; w[2] = a[2]; w[3] = a[3];
                w[4] = b[0]; w[5] = b[1]; w[6] = b[2]; w[7] = b[3];
                *(short8*)(dst + u * 4) = w;
            }
        }
        return;
    }

    const float scale = (QSC && bn < 1024) ? QSCALE : 1.0f;
    #pragma unroll
    for (int i = 0; i < 4; ++i) {
        #pragma unroll
        for (int j = 0; j < 4; ++j) {
            #pragma unroll
            for (int r = 0; r < 4; ++r) {
                int row = bm + wr * 64 + i * 16 + quad * 4 + r;
                int col = bn + wc * 64 + j * 16 + l16;
                float v = acc[i][j][r] * scale;
                storeC(C, (size_t)row * N + col, v);
            }
        }
    }
}

// ---------------------------------------------------------------------------
// gemm64: BM=64, BN=128 variant of the same structure for the out-proj GEMM.
// Grid (8, 64) = 512 blocks -> 2 blocks/CU. 4 waves 2x2, per-wave 32x64.
// ---------------------------------------------------------------------------
template <bool ADD_BIAS, typename TC>
__global__ __launch_bounds__(256, 4) void gemm64(
    const short* __restrict__ A, const short* __restrict__ Bt,
    const float* __restrict__ bias, TC* __restrict__ C,
    int M, int N, int K, int lda)
{
    __shared__ short A_s0[64 * 32];
    __shared__ short A_s1[64 * 32];
    __shared__ short B_s0[128 * 32];
    __shared__ short B_s1[128 * 32];
    const int tid  = threadIdx.x;
    const int lane = tid & 63;
    const int wave = tid >> 6;
    const int quad = lane >> 4;
    const int l16  = lane & 15;
    const int wr   = wave >> 1;     // M half (32 rows)
    const int wc   = wave & 1;      // N half (64 cols)
    const int bm   = blockIdx.y * 64;
    const int bn   = blockIdx.x * 128;

    f32x4 acc[2][4];
    #pragma unroll
    for (int i = 0; i < 2; ++i)
        #pragma unroll
        for (int j = 0; j < 4; ++j)
            acc[i][j] = f32x4{0.f, 0.f, 0.f, 0.f};

    const int srow = tid >> 2;
    const int schk = tid & 3;
    const int sg   = (schk ^ ((srow >> 1) & 3)) * 8;
    const short* ap0 = A  + (size_t)(bm + srow) * lda + sg;
    const short* bp0 = Bt + (size_t)(bn + srow) * K   + sg;
    const short* bp1 = Bt + (size_t)(bn + 64 + srow) * K + sg;
    const int lofs0 = wave * 512;
    const int lofs1 = 2048 + wave * 512;

    const int xr = (quad ^ ((l16 >> 1) & 3)) * 8;

#define STAGE_H(As, Bs, koff)                  \
    gload16(ap0 + (koff), (As) + lofs0);       \
    gload16(bp0 + (koff), (Bs) + lofs0);       \
    gload16(bp1 + (koff), (Bs) + lofs1);

#define COMPUTE_H(As, Bs)                                                   \
    {                                                                       \
        short8 a[2], b[4];                                                  \
        _Pragma("unroll")                                                   \
        for (int i = 0; i < 2; ++i)                                         \
            a[i] = *(const short8*)&(As)[(wr * 32 + i * 16 + l16) * 32 + xr]; \
        _Pragma("unroll")                                                   \
        for (int j = 0; j < 4; ++j)                                         \
            b[j] = *(const short8*)&(Bs)[(wc * 64 + j * 16 + l16) * 32 + xr]; \
        _Pragma("unroll")                                                   \
        for (int i = 0; i < 2; ++i)                                         \
            _Pragma("unroll")                                               \
            for (int j = 0; j < 4; ++j)                                     \
                acc[i][j] = mfma_bf16(a[i], b[j], acc[i][j]);               \
    }

    STAGE_H(A_s0, B_s0, 0);
    __syncthreads();

    for (int k0 = 0; k0 < K; k0 += 64) {
        if (k0 + 32 < K) { STAGE_H(A_s1, B_s1, k0 + 32); }
        COMPUTE_H(A_s0, B_s0);
        __syncthreads();
        if (k0 + 64 < K) { STAGE_H(A_s0, B_s0, k0 + 64); }
        COMPUTE_H(A_s1, B_s1);
        __syncthreads();
    }
#undef STAGE_H
#undef COMPUTE_H

    #pragma unroll
    for (int i = 0; i < 2; ++i) {
        #pragma unroll
        for (int j = 0; j < 4; ++j) {
            #pragma unroll
            for (int r = 0; r < 4; ++r) {
                int row = bm + wr * 32 + i * 16 + quad * 4 + r;
                int col = bn + wc * 64 + j * 16 + l16;
                float v = acc[i][j][r];
                if (ADD_BIAS) v += bias[col];
                storeC(C, (size_t)row * N + col, v);
            }
        }
    }
}

// ---------------------------------------------------------------------------
// Flash attention v7 + XCD-aware (bh,qb) swizzle (round 15).
// The 16 q-blocks sharing one (b,h) K/V panel (512 KB) were scattered
// round-robin across the 8 XCD L2s -> FETCH 69.7 MB vs ~32 ideal, and the
// per-tile reg-prefetch pays HBM-miss latency (~900 cy) instead of L2-hit
// (~200 cy) — attn is latency-bound, so this is the binding term the
// v8/v9/v10 restructures couldn't fix without occupancy cost.
// Bijective remap (512 blocks, lid -> (lid&7, (lid>>3)&3, lid>>5)):
//   XCD r owns bh in [r*4, r*4+4) x all 16 q-blocks; 4 panels = 2 MB < 4 MB L2.
// Compute structure byte-identical to v7 (best: 57.2-61.5 µs over 6 runs).
// grid (2048/128, 32) = 512 blocks.
// ---------------------------------------------------------------------------
__global__ __launch_bounds__(256) void attn128(
    short* __restrict__ qkv, const short* __restrict__ vt)
{
    __shared__ short Ks[128 * 72];   // [key][dim]
    __shared__ short Vs[16 * 520];   // [g][dim][k&7], g = key>>3 (tile-local)

    const int tid  = threadIdx.x;
    const int lane = tid & 63;
    const int wave = tid >> 6;
    const int quad = lane >> 4;
    const int l16  = lane & 15;
    // XCD-aware swizzle: consecutive dispatch ids round-robin XCDs; give
    // XCD r a contiguous bh range so its L2 keeps those K/V panels warm.
    const int lid  = blockIdx.y * gridDim.x + blockIdx.x;   // 0..511
    const int bh   = (lid & 7) * 4 + ((lid >> 3) & 3);
    const int qb   = (lid >> 5) * 128;
    const int b = bh >> 4, h = bh & 15;
    const size_t rowbase = (size_t)b * 2048;

    // Q fragments for 2 q-groups (B-op for S^T), pre-scaled by log2e/32
    short8 aq[2][2];
    #pragma unroll
    for (int qg = 0; qg < 2; ++qg) {
        const short* qp = qkv + (rowbase + qb + wave * 32 + qg * 16 + l16) * 3072 + h * 64;
        aq[qg][0] = *(const short8*)(qp + quad * 8);
        aq[qg][1] = *(const short8*)(qp + 32 + quad * 8);
    }

    f32x4 o[2][4];
    #pragma unroll
    for (int qg = 0; qg < 2; ++qg)
        #pragma unroll
        for (int c = 0; c < 4; ++c) o[qg][c] = f32x4{0.f, 0.f, 0.f, 0.f};
    float rsum[2] = {0.f, 0.f};   // softmax denom partials for q = l16

    const int kkey = tid >> 1, kdc = (tid & 1) * 32;
    const int vdim = tid >> 2, vg0 = (tid & 3) * 4;
    const short* kbase = qkv + (rowbase + kkey) * 3072 + 1024 + h * 64 + kdc;
    const short* vbase = vt + ((size_t)bh * 64 + vdim) * 2048 + vg0 * 8;

    // prefetch tile 0
    short8 kr0 = *(const short8*)(kbase);
    short8 kr1 = *(const short8*)(kbase + 8);
    short8 kr2 = *(const short8*)(kbase + 16);
    short8 kr3 = *(const short8*)(kbase + 24);
    short8 vr0 = *(const short8*)(vbase);
    short8 vr1 = *(const short8*)(vbase + 8);
    short8 vr2 = *(const short8*)(vbase + 16);
    short8 vr3 = *(const short8*)(vbase + 24);

    for (int kt = 0; kt < 2048; kt += 128) {
        __syncthreads();                      // prior-tile LDS readers done
        *(short8*)&Ks[kkey * 72 + kdc]      = kr0;
        *(short8*)&Ks[kkey * 72 + kdc + 8]  = kr1;
        *(short8*)&Ks[kkey * 72 + kdc + 16] = kr2;
        *(short8*)&Ks[kkey * 72 + kdc + 24] = kr3;
        *(short8*)&Vs[(vg0 + 0) * 520 + vdim * 8] = vr0;
        *(short8*)&Vs[(vg0 + 1) * 520 + vdim * 8] = vr1;
        *(short8*)&Vs[(vg0 + 2) * 520 + vdim * 8] = vr2;
        *(short8*)&Vs[(vg0 + 3) * 520 + vdim * 8] = vr3;
        if (kt + 128 < 2048) {                // prefetch next tile
            const short* kp = kbase + (size_t)(kt + 128) * 3072;
            kr0 = *(const short8*)(kp);
            kr1 = *(const short8*)(kp + 8);
            kr2 = *(const short8*)(kp + 16);
            kr3 = *(const short8*)(kp + 24);
            const short* vp = vbase + kt + 128;
            vr0 = *(const short8*)(vp);
            vr1 = *(const short8*)(vp + 8);
            vr2 = *(const short8*)(vp + 16);
            vr3 = *(const short8*)(vp + 24);
        }
        __syncthreads();                      // tile visible

        // two chunks of 64 keys: S^T -> exp2 -> PV
        #pragma unroll
        for (int cc = 0; cc < 2; ++cc) {
            // S^T: lane holds S[q=l16][key=(cc*4+c4)*16+quad*4+r], per q-group
            f32x4 st[2][4];
            #pragma unroll
            for (int c4 = 0; c4 < 4; ++c4) {
                const int c = cc * 4 + c4;
                short8 ka0 = *(const short8*)&Ks[(c * 16 + l16) * 72 + quad * 8];
                short8 ka1 = *(const short8*)&Ks[(c * 16 + l16) * 72 + 32 + quad * 8];
                #pragma unroll
                for (int qg = 0; qg < 2; ++qg) {
                    f32x4 z = f32x4{0.f, 0.f, 0.f, 0.f};
                    z = mfma_bf16(ka0, aq[qg][0], z);
                    st[qg][c4] = mfma_bf16(ka1, aq[qg][1], z);
                }
            }
            // p = exp2(s'): bare v_exp_f32 + v_cvt_pk_bf16_f32 packing
            uint2v pa[2][4];
            #pragma unroll
            for (int qg = 0; qg < 2; ++qg) {
                #pragma unroll
                for (int c4 = 0; c4 < 4; ++c4) {
                    float p0 = fexp2(st[qg][c4][0]);
                    float p1 = fexp2(st[qg][c4][1]);
                    float p2 = fexp2(st[qg][c4][2]);
                    float p3 = fexp2(st[qg][c4][3]);
                    rsum[qg] += (p0 + p1) + (p2 + p3);
                    uint2v pk;
                    pk[0] = pkbf(p0, p1);
                    pk[1] = pkbf(p2, p3);
                    pa[qg][c4] = pk;
                }
            }
            // PV: bv read once, used by both q-groups
            #pragma unroll
            for (int c2 = 0; c2 < 4; ++c2) {
                #pragma unroll
                for (int c4 = 0; c4 < 4; ++c4) {
                    const int c = cc * 4 + c4;
                    uint2v bv = *(const uint2v*)&Vs[(2 * c + (quad >> 1)) * 520
                                                    + (c2 * 16 + l16) * 8
                                                    + (quad & 1) * 4];
                    #pragma unroll
                    for (int qg = 0; qg < 2; ++qg)
                        o[qg][c2] = mfma16(pa[qg][c4], bv, o[qg][c2]);
                }
            }
        }
    }

    // full denom for q=l16: sum over the 4 quad-lanes
    #pragma unroll
    for (int qg = 0; qg < 2; ++qg) {
        rsum[qg] += __shfl_xor(rsum[qg], 16, 64);
        rsum[qg] += __shfl_xor(rsum[qg], 32, 64);
    }

    // epilogue: o rows are q=quad*4+r; fetch that q's denom from lane q
    #pragma unroll
    for (int qg = 0; qg < 2; ++qg) {
        #pragma unroll
        for (int r = 0; r < 4; ++r) {
            float inv = 1.0f / __shfl(rsum[qg], quad * 4 + r, 64);
            size_t row = rowbase + qb + wave * 32 + qg * 16 + quad * 4 + r;
            #pragma unroll
            for (int c2 = 0; c2 < 4; ++c2)
                qkv[row * 3072 + h * 64 + c2 * 16 + l16] = f2b(o[qg][c2][r] * inv);
        }
    }
}

// ---------------------------------------------------------------------------
extern "C" void kernel_launch(void* const* d_in, const int* in_sizes, int n_in,
                              void* d_out, int out_size, void* d_ws, size_t ws_size,
                              hipStream_t stream)
{
    const float* x    = (const float*)d_in[0];   // (2,2048,1024) fp32
    const float* Wqkv = (const float*)d_in[2];   // (1024,3072) fp32
    const float* Wout = (const float*)d_in[3];   // (1024,1024) fp32
    const float* bout = (const float*)d_in[4];   // (1024,) fp32
    float* out = (float*)d_out;                  // (2,2048,1024) fp32

    // Buffer map:
    //   ws (32 MiB): qkv 24 MiB | wqkvt 6 MiB | woutt 2 MiB
    //   d_out (16 MiB): xbf lower 8 MiB (dead after gemm1)
    //                   vt  upper 8 MiB (written by gemm1's fused epilogue,
    //                                    dead after attn)
    //   gemm2 overwrites all of d_out last.
    short* qkv   = (short*)d_ws;                        // 4096 x 3072 bf16
    short* wqkvt = qkv + (size_t)4096 * 3072;           // 3072 x 1024 bf16
    short* woutt = wqkvt + (size_t)3072 * 1024;         // 1024 x 1024 bf16
    short* xbf   = (short*)d_out;                       // 4096 x 1024 bf16
    short* vtbuf = xbf + (size_t)4096 * 1024;           // 32 x 64 x 2048 bf16

    dim3 blk(256);
    prep<<<dim3(3072), blk, 0, stream>>>(x, xbf, Wqkv, wqkvt, Wout, woutt);
    gemm128<true, short><<<dim3(24, 32), blk, 0, stream>>>(
        xbf, wqkvt, qkv, vtbuf, 2048, 4096, 3072, 1024, 1024);
    attn128<<<dim3(16, 32), blk, 0, stream>>>(qkv, vtbuf);
    gemm64<true, float><<<dim3(8, 64), blk, 0, stream>>>(
        qkv, woutt, bout, out, 4096, 1024, 1024, 3072);
}

// Round 16
// 182.785 us; speedup vs baseline: 1.0803x; 1.0158x over previous
//
#include <hip/hip_runtime.h>

typedef __attribute__((ext_vector_type(8))) short short8;
typedef __attribute__((ext_vector_type(4))) short s16x4;
typedef __attribute__((ext_vector_type(8))) __bf16 bf16x8;
typedef __attribute__((ext_vector_type(4))) __bf16 bf16x4;
typedef __attribute__((ext_vector_type(2))) __bf16 bf16x2;
typedef __attribute__((ext_vector_type(4))) float f32x4;
typedef __attribute__((ext_vector_type(2))) float f32x2;
typedef __attribute__((ext_vector_type(4))) unsigned uint4v;
typedef __attribute__((ext_vector_type(2))) unsigned uint2v;

__device__ inline f32x4 mfma_bf16(short8 a, short8 b, f32x4 c) {
    return __builtin_amdgcn_mfma_f32_16x16x32_bf16(
        __builtin_bit_cast(bf16x8, a), __builtin_bit_cast(bf16x8, b), c, 0, 0, 0);
}
// K=16 bf16 MFMA: A-frag layout A[m=l16][k=quad*4+j] == C/D layout of a prior
// MFMA transposed -> P needs no layout transform.
__device__ inline f32x4 mfma16(uint2v a, uint2v b, f32x4 c) {
#if __has_builtin(__builtin_amdgcn_mfma_f32_16x16x16_bf16)
    return __builtin_amdgcn_mfma_f32_16x16x16_bf16(
        __builtin_bit_cast(bf16x4, a), __builtin_bit_cast(bf16x4, b), c, 0, 0, 0);
#else
    return __builtin_amdgcn_mfma_f32_16x16x16bf16_1k(
        __builtin_bit_cast(s16x4, a), __builtin_bit_cast(s16x4, b), c, 0, 0, 0);
#endif
}

// fast exp2: bare v_exp_f32
__device__ inline float fexp2(float x) {
#if __has_builtin(__builtin_amdgcn_exp2f)
    return __builtin_amdgcn_exp2f(x);
#else
    return exp2f(x);
#endif
}

// fp32 -> bf16 via HW convert (v_cvt_pk_bf16_f32 on gfx950), RNE
__device__ inline short f2b(float f) {
    __bf16 h = (__bf16)f;
    return __builtin_bit_cast(short, h);
}
__device__ inline unsigned pkbf(float a, float b) {
    f32x2 v; v[0] = a; v[1] = b;
    bf16x2 h = __builtin_convertvector(v, bf16x2);
    return __builtin_bit_cast(unsigned, h);
}

__device__ inline short8 ld8(const short* p) { return *(const short8*)p; }
__device__ inline short8 ld8(const float* p) {
    f32x4 a = *(const f32x4*)p;
    f32x4 b = *(const f32x4*)(p + 4);
    uint4v q;
    q[0] = pkbf(a[0], a[1]); q[1] = pkbf(a[2], a[3]);
    q[2] = pkbf(b[0], b[1]); q[3] = pkbf(b[2], b[3]);
    return __builtin_bit_cast(short8, q);
}
__device__ inline void storeC(short* C, size_t i, float v) { C[i] = f2b(v); }
__device__ inline void storeC(float* C, size_t i, float v) { C[i] = v; }

// async global->LDS DMA, 16B per lane. LDS dest must be wave-uniform base;
// HW writes lane l at base + l*16 (m104/m108: no per-lane LDS scatter).
__device__ inline void gload16(const short* g, short* l) {
    __builtin_amdgcn_global_load_lds(
        (const __attribute__((address_space(1))) unsigned*)g,
        (__attribute__((address_space(3))) unsigned*)l, 16, 0, 0);
}

// log2(e)/32 : folded into Q so softmax uses exp2 (bare v_exp_f32)
#define QSCALE 0.04508422052265167f

// ---------------------------------------------------------------------------
// Fused prep: one launch does
//   blocks [0,2048):    x fp32 -> xbf bf16 bulk convert
//   blocks [2048,2816): Wqkv [1024][3072] -> wqkvt [3072][1024] bf16 k-major
//   blocks [2816,3072): Wout [1024][1024] -> woutt [1024][1024] bf16 k-major
// ---------------------------------------------------------------------------
__global__ __launch_bounds__(256) void prep(
    const float* __restrict__ x, short* __restrict__ xb,
    const float* __restrict__ Wqkv, short* __restrict__ wqkvt,
    const float* __restrict__ Wout, short* __restrict__ woutt)
{
    const int bid = blockIdx.x;
    const int tid = threadIdx.x;
    if (bid < 2048) {
        size_t i = ((size_t)bid * 256 + tid) * 8;
        *(short8*)(xb + i) = ld8(x + i);
        return;
    }
    __shared__ short T[64 * 72];
    const float* W; short* Wt; int K, N, n0, k0;
    if (bid < 2816) {
        const int b2 = bid - 2048;
        W = Wqkv; Wt = wqkvt; K = 1024; N = 3072;
        n0 = (b2 % 48) * 64; k0 = (b2 / 48) * 64;
    } else {
        const int b3 = bid - 2816;
        W = Wout; Wt = woutt; K = 1024; N = 1024;
        n0 = (b3 & 15) * 64; k0 = (b3 >> 4) * 64;
    }
    {
        const int kl = tid >> 2, nc = (tid & 3) * 16;
        const float* src = W + (size_t)(k0 + kl) * N + n0 + nc;
        float v[16];
        *(f32x4*)&v[0]  = *(const f32x4*)(src + 0);
        *(f32x4*)&v[4]  = *(const f32x4*)(src + 4);
        *(f32x4*)&v[8]  = *(const f32x4*)(src + 8);
        *(f32x4*)&v[12] = *(const f32x4*)(src + 12);
        #pragma unroll
        for (int j = 0; j < 16; ++j) T[(nc + j) * 72 + kl] = f2b(v[j]);
    }
    __syncthreads();
    {
        const int nl = tid >> 2, kc = (tid & 3) * 16;
        short8 w0 = *(const short8*)&T[nl * 72 + kc];
        short8 w1 = *(const short8*)&T[nl * 72 + kc + 8];
        short* dst = Wt + (size_t)(n0 + nl) * K + k0 + kc;
        *(short8*)dst = w0;
        *(short8*)(dst + 8) = w1;
    }
}

// ---------------------------------------------------------------------------
// GEMM: global_load_lds DMA staging + double-buffered LDS 2-phase pipeline.
// C = A @ Bt^T (+bias). 128x128 tile, BK=32, 4 waves 2x2 (64x64 each).
// STAGE(next) issued BEFORE COMPUTE(cur); one barrier per K-step.
// Bank-swizzle: source chunk c ^ ((row>>1)&3), read slot quad ^ ((l16>>1)&3).
// QSC: scale cols<1024 by log2(e)/32 (Q pre-scale for exp2 softmax).
//
// FUSED V-TRANSPOSE: for blocks with bn >= vstart (the V panel of the qkv
// projection), the epilogue writes vt[(b*16+h)*64+dim][tok] instead of C —
// eliminating the separate vtrans kernel and its 16 MB HBM round-trip.
// ---------------------------------------------------------------------------
template <bool QSC, typename TC>
__global__ __launch_bounds__(256, 4) void gemm128(
    const short* __restrict__ A, const short* __restrict__ Bt,
    TC* __restrict__ C, short* __restrict__ vtout, int vstart,
    int M, int N, int K, int lda)
{
    __shared__ short SM[128 * 128];       // 4 x (128*32) tile buffers, merged
    short* const A_s0 = SM;
    short* const A_s1 = SM + 4096;
    short* const B_s0 = SM + 8192;
    short* const B_s1 = SM + 12288;
    const int tid  = threadIdx.x;
    const int lane = tid & 63;
    const int wave = tid >> 6;
    const int quad = lane >> 4;
    const int l16  = lane & 15;
    const int wr   = wave >> 1;
    const int wc   = wave & 1;
    const int bm   = blockIdx.y * 128;
    const int bn   = blockIdx.x * 128;

    f32x4 acc[4][4];
    #pragma unroll
    for (int i = 0; i < 4; ++i)
        #pragma unroll
        for (int j = 0; j < 4; ++j)
            acc[i][j] = f32x4{0.f, 0.f, 0.f, 0.f};

    const int srow = tid >> 2;
    const int schk = tid & 3;
    const int sg   = (schk ^ ((srow >> 1) & 3)) * 8;
    const short* ap0 = A  + (size_t)(bm + srow) * lda + sg;
    const short* ap1 = A  + (size_t)(bm + 64 + srow) * lda + sg;
    const short* bp0 = Bt + (size_t)(bn + srow) * K   + sg;
    const short* bp1 = Bt + (size_t)(bn + 64 + srow) * K   + sg;
    const int lofs0 = wave * 512;
    const int lofs1 = 2048 + wave * 512;

    const int xr = (quad ^ ((l16 >> 1) & 3)) * 8;

#define STAGE_G(As, Bs, koff)                  \
    gload16(ap0 + (koff), (As) + lofs0);       \
    gload16(ap1 + (koff), (As) + lofs1);       \
    gload16(bp0 + (koff), (Bs) + lofs0);       \
    gload16(bp1 + (koff), (Bs) + lofs1);

#define COMPUTE_G(As, Bs)                                                   \
    {                                                                       \
        short8 a[4], b[4];                                                  \
        _Pragma("unroll")                                                   \
        for (int i = 0; i < 4; ++i)                                         \
            a[i] = *(const short8*)&(As)[(wr * 64 + i * 16 + l16) * 32 + xr]; \
        _Pragma("unroll")                                                   \
        for (int j = 0; j < 4; ++j)                                         \
            b[j] = *(const short8*)&(Bs)[(wc * 64 + j * 16 + l16) * 32 + xr]; \
        _Pragma("unroll")                                                   \
        for (int i = 0; i < 4; ++i)                                         \
            _Pragma("unroll")                                               \
            for (int j = 0; j < 4; ++j)                                     \
                acc[i][j] = mfma_bf16(a[i], b[j], acc[i][j]);               \
    }

    STAGE_G(A_s0, B_s0, 0);
    __syncthreads();

    for (int k0 = 0; k0 < K; k0 += 64) {
        if (k0 + 32 < K) { STAGE_G(A_s1, B_s1, k0 + 32); }
        COMPUTE_G(A_s0, B_s0);
        __syncthreads();
        if (k0 + 64 < K) { STAGE_G(A_s0, B_s0, k0 + 64); }
        COMPUTE_G(A_s1, B_s1);
        __syncthreads();
    }
#undef STAGE_G
#undef COMPUTE_G

    if (vtout != nullptr && bn >= vstart) {
        // ---- fused V-transpose epilogue (block-uniform branch) ----
        // stage acc into SM[col][tok] with granule-XOR swizzle
        #pragma unroll
        for (int i = 0; i < 4; ++i) {
            #pragma unroll
            for (int j = 0; j < 4; ++j) {
                const int col  = wc * 64 + j * 16 + l16;
                const int tok0 = wr * 64 + i * 16 + quad * 4;
                const int G    = (tok0 >> 2) ^ (col & 31);
                s16x4 v4;
                #pragma unroll
                for (int r = 0; r < 4; ++r) v4[r] = f2b(acc[i][j][r]);
                *(s16x4*)&SM[col * 128 + G * 4] = v4;
            }
        }
        __syncthreads();
        // write out: thread t owns (col=t>>1, toks (t&1)*64 .. +63)
        {
            const int col2  = tid >> 1;
            const int gc    = col2 & 31;
            const int gbase = (tid & 1) * 16;          // granule base (4 toks each)
            const short* base = SM + col2 * 128;
            const int gcol = bn + col2 - 2048;         // V panel col
            const int hh   = gcol >> 6, dim = gcol & 63;
            const int bb   = bm >> 11;                 // batch (tiles don't straddle)
            short* dst = vtout + ((size_t)(bb * 16 + hh) * 64 + dim) * 2048
                               + (bm & 2047) + gbase * 4;
            #pragma unroll
            for (int u = 0; u < 16; u += 2) {
                s16x4 a = *(const s16x4*)&base[((gbase + u)     ^ gc) * 4];
                s16x4 b = *(const s16x4*)&base[((gbase + u + 1) ^ gc) * 4];
                short8 w;
                w[0] = a[0]; w[1] = a[1]; w[2] = a[2]; w[3] = a[3];
                w[4] = b[0]; w[5] = b[1]; w[6] = b[2]; w[7] = b[3];
                *(short8*)(dst + u * 4) = w;
            }
        }
        return;
    }

    const float scale = (QSC && bn < 1024) ? QSCALE : 1.0f;
    #pragma unroll
    for (int i = 0; i < 4; ++i) {
        #pragma unroll
        for (int j = 0; j < 4; ++j) {
            #pragma unroll
            for (int r = 0; r < 4; ++r) {
                int row = bm + wr * 64 + i * 16 + quad * 4 + r;
                int col = bn + wc * 64 + j * 16 + l16;
                float v = acc[i][j][r] * scale;
                storeC(C, (size_t)row * N + col, v);
            }
        }
    }
}

// ---------------------------------------------------------------------------
// gemm64 v2: BM=64, BN=128, BK=64 dbuf (round 16). Out-proj was the worst
// per-FLOP kernel: at BK=32 each wave had only 8 MFMA (~38 cyc) per
// stage+barrier cycle (m233: that overhead dominates 2-phase loops).
// BK=64 doubles MFMA/barrier (16/wave) and halves barrier count (32->16).
// LDS 2 x (8KB A + 16KB B) = 48KB -> still 2-3 blocks/CU (avoids m132's
// 64KB occupancy cliff). Rows are 8 chunks of 8 shorts; store global chunk
// g at slot g^(row&7) (pre-swizzled source), read slot (quad+4*h)^(l16&7)
// for K-half h — bijective per row, 2-way banks (free). (row+32)&7==row&7
// so one sg serves all issue rows. Grid (8,64)=512 -> 2 blocks/CU.
// ---------------------------------------------------------------------------
template <bool ADD_BIAS, typename TC>
__global__ __launch_bounds__(256, 4) void gemm64(
    const short* __restrict__ A, const short* __restrict__ Bt,
    const float* __restrict__ bias, TC* __restrict__ C,
    int M, int N, int K, int lda)
{
    __shared__ short A_s0[64 * 64];      // 8 KB
    __shared__ short A_s1[64 * 64];
    __shared__ short B_s0[128 * 64];     // 16 KB
    __shared__ short B_s1[128 * 64];
    const int tid  = threadIdx.x;
    const int lane = tid & 63;
    const int wave = tid >> 6;
    const int quad = lane >> 4;
    const int l16  = lane & 15;
    const int wr   = wave >> 1;     // M half (32 rows)
    const int wc   = wave & 1;      // N half (64 cols)
    const int bm   = blockIdx.y * 64;
    const int bn   = blockIdx.x * 128;

    f32x4 acc[2][4];
    #pragma unroll
    for (int i = 0; i < 2; ++i)
        #pragma unroll
        for (int j = 0; j < 4; ++j)
            acc[i][j] = f32x4{0.f, 0.f, 0.f, 0.f};

    // staging: thread t -> row (t>>3) within each 32-row issue-group,
    // slot t&7; source chunk XOR-swizzled: g = slot ^ (row&7)
    const int srow = tid >> 3;            // 0..31
    const int sslt = tid & 7;             // 0..7
    const int sg   = (sslt ^ (srow & 7)) * 8;
    const short* ap0 = A  + (size_t)(bm + srow) * lda + sg;
    const short* ap1 = A  + (size_t)(bm + 32 + srow) * lda + sg;
    const short* bq0 = Bt + (size_t)(bn + srow) * K + sg;
    const short* bq1 = Bt + (size_t)(bn + 32 + srow) * K + sg;
    const short* bq2 = Bt + (size_t)(bn + 64 + srow) * K + sg;
    const short* bq3 = Bt + (size_t)(bn + 96 + srow) * K + sg;
    const int lofsW = wave * 512;         // lane l lands at issue_base + t*16B

    // read-side slot XOR (row bits mod 8 == l16&7 for all fragment rows)
    const int lx8 = (l16 & 7);

#define STAGE_H(As, Bs, koff)                       \
    gload16(ap0 + (koff), (As) + lofsW);            \
    gload16(ap1 + (koff), (As) + 2048 + lofsW);     \
    gload16(bq0 + (koff), (Bs) + lofsW);            \
    gload16(bq1 + (koff), (Bs) + 2048 + lofsW);     \
    gload16(bq2 + (koff), (Bs) + 4096 + lofsW);     \
    gload16(bq3 + (koff), (Bs) + 6144 + lofsW);

#define COMPUTE_H(As, Bs)                                                     \
    {                                                                         \
        _Pragma("unroll")                                                     \
        for (int h = 0; h < 2; ++h) {                                         \
            const int slt = ((quad + 4 * h) ^ lx8) * 8;                       \
            short8 a[2], b[4];                                                \
            _Pragma("unroll")                                                 \
            for (int i = 0; i < 2; ++i)                                       \
                a[i] = *(const short8*)&(As)[(wr * 32 + i * 16 + l16) * 64 + slt]; \
            _Pragma("unroll")                                                 \
            for (int j = 0; j < 4; ++j)                                       \
                b[j] = *(const short8*)&(Bs)[(wc * 64 + j * 16 + l16) * 64 + slt]; \
            _Pragma("unroll")                                                 \
            for (int i = 0; i < 2; ++i)                                       \
                _Pragma("unroll")                                             \
                for (int j = 0; j < 4; ++j)                                   \
                    acc[i][j] = mfma_bf16(a[i], b[j], acc[i][j]);             \
        }                                                                     \
    }

    STAGE_H(A_s0, B_s0, 0);
    __syncthreads();

    // K = 1024 -> 16 tiles of BK=64, 2x unrolled for static buffer names
    for (int k0 = 0; k0 < K; k0 += 128) {
        if (k0 + 64 < K) { STAGE_H(A_s1, B_s1, k0 + 64); }
        COMPUTE_H(A_s0, B_s0);
        __syncthreads();
        if (k0 + 128 < K) { STAGE_H(A_s0, B_s0, k0 + 128); }
        COMPUTE_H(A_s1, B_s1);
        __syncthreads();
    }
#undef STAGE_H
#undef COMPUTE_H

    #pragma unroll
    for (int i = 0; i < 2; ++i) {
        #pragma unroll
        for (int j = 0; j < 4; ++j) {
            #pragma unroll
            for (int r = 0; r < 4; ++r) {
                int row = bm + wr * 32 + i * 16 + quad * 4 + r;
                int col = bn + wc * 64 + j * 16 + l16;
                float v = acc[i][j][r];
                if (ADD_BIAS) v += bias[col];
                storeC(C, (size_t)row * N + col, v);
            }
        }
    }
}

// ---------------------------------------------------------------------------
// Flash attention v7 + XCD-aware (bh,qb) swizzle (round 15: FETCH 69.7->12.3
// MB; K/V panels L2-resident). Compute structure = v7 local optimum
// (ledger: q-split 64.6, key-split 86.6/60.4, dbuf 67.6 all regressed).
// 32 q-rows per wave; S^T MFMA -> exp2 -> direct K=16 PV; ctx in-place.
// grid (2048/128, 32) = 512 blocks.
// ---------------------------------------------------------------------------
__global__ __launch_bounds__(256) void attn128(
    short* __restrict__ qkv, const short* __restrict__ vt)
{
    __shared__ short Ks[128 * 72];   // [key][dim]
    __shared__ short Vs[16 * 520];   // [g][dim][k&7], g = key>>3 (tile-local)

    const int tid  = threadIdx.x;
    const int lane = tid & 63;
    const int wave = tid >> 6;
    const int quad = lane >> 4;
    const int l16  = lane & 15;
    // XCD-aware swizzle: give XCD r a contiguous bh range so its L2 keeps
    // those K/V panels warm (bijective over 512 blocks).
    const int lid  = blockIdx.y * gridDim.x + blockIdx.x;   // 0..511
    const int bh   = (lid & 7) * 4 + ((lid >> 3) & 3);
    const int qb   = (lid >> 5) * 128;
    const int b = bh >> 4, h = bh & 15;
    const size_t rowbase = (size_t)b * 2048;

    // Q fragments for 2 q-groups (B-op for S^T), pre-scaled by log2e/32
    short8 aq[2][2];
    #pragma unroll
    for (int qg = 0; qg < 2; ++qg) {
        const short* qp = qkv + (rowbase + qb + wave * 32 + qg * 16 + l16) * 3072 + h * 64;
        aq[qg][0] = *(const short8*)(qp + quad * 8);
        aq[qg][1] = *(const short8*)(qp + 32 + quad * 8);
    }

    f32x4 o[2][4];
    #pragma unroll
    for (int qg = 0; qg < 2; ++qg)
        #pragma unroll
        for (int c = 0; c < 4; ++c) o[qg][c] = f32x4{0.f, 0.f, 0.f, 0.f};
    float rsum[2] = {0.f, 0.f};   // softmax denom partials for q = l16

    const int kkey = tid >> 1, kdc = (tid & 1) * 32;
    const int vdim = tid >> 2, vg0 = (tid & 3) * 4;
    const short* kbase = qkv + (rowbase + kkey) * 3072 + 1024 + h * 64 + kdc;
    const short* vbase = vt + ((size_t)bh * 64 + vdim) * 2048 + vg0 * 8;

    // prefetch tile 0
    short8 kr0 = *(const short8*)(kbase);
    short8 kr1 = *(const short8*)(kbase + 8);
    short8 kr2 = *(const short8*)(kbase + 16);
    short8 kr3 = *(const short8*)(kbase + 24);
    short8 vr0 = *(const short8*)(vbase);
    short8 vr1 = *(const short8*)(vbase + 8);
    short8 vr2 = *(const short8*)(vbase + 16);
    short8 vr3 = *(const short8*)(vbase + 24);

    for (int kt = 0; kt < 2048; kt += 128) {
        __syncthreads();                      // prior-tile LDS readers done
        *(short8*)&Ks[kkey * 72 + kdc]      = kr0;
        *(short8*)&Ks[kkey * 72 + kdc + 8]  = kr1;
        *(short8*)&Ks[kkey * 72 + kdc + 16] = kr2;
        *(short8*)&Ks[kkey * 72 + kdc + 24] = kr3;
        *(short8*)&Vs[(vg0 + 0) * 520 + vdim * 8] = vr0;
        *(short8*)&Vs[(vg0 + 1) * 520 + vdim * 8] = vr1;
        *(short8*)&Vs[(vg0 + 2) * 520 + vdim * 8] = vr2;
        *(short8*)&Vs[(vg0 + 3) * 520 + vdim * 8] = vr3;
        if (kt + 128 < 2048) {                // prefetch next tile
            const short* kp = kbase + (size_t)(kt + 128) * 3072;
            kr0 = *(const short8*)(kp);
            kr1 = *(const short8*)(kp + 8);
            kr2 = *(const short8*)(kp + 16);
            kr3 = *(const short8*)(kp + 24);
            const short* vp = vbase + kt + 128;
            vr0 = *(const short8*)(vp);
            vr1 = *(const short8*)(vp + 8);
            vr2 = *(const short8*)(vp + 16);
            vr3 = *(const short8*)(vp + 24);
        }
        __syncthreads();                      // tile visible

        // two chunks of 64 keys: S^T -> exp2 -> PV
        #pragma unroll
        for (int cc = 0; cc < 2; ++cc) {
            // S^T: lane holds S[q=l16][key=(cc*4+c4)*16+quad*4+r], per q-group
            f32x4 st[2][4];
            #pragma unroll
            for (int c4 = 0; c4 < 4; ++c4) {
                const int c = cc * 4 + c4;
                short8 ka0 = *(const short8*)&Ks[(c * 16 + l16) * 72 + quad * 8];
                short8 ka1 = *(const short8*)&Ks[(c * 16 + l16) * 72 + 32 + quad * 8];
                #pragma unroll
                for (int qg = 0; qg < 2; ++qg) {
                    f32x4 z = f32x4{0.f, 0.f, 0.f, 0.f};
                    z = mfma_bf16(ka0, aq[qg][0], z);
                    st[qg][c4] = mfma_bf16(ka1, aq[qg][1], z);
                }
            }
            // p = exp2(s'): bare v_exp_f32 + v_cvt_pk_bf16_f32 packing
            uint2v pa[2][4];
            #pragma unroll
            for (int qg = 0; qg < 2; ++qg) {
                #pragma unroll
                for (int c4 = 0; c4 < 4; ++c4) {
                    float p0 = fexp2(st[qg][c4][0]);
                    float p1 = fexp2(st[qg][c4][1]);
                    float p2 = fexp2(st[qg][c4][2]);
                    float p3 = fexp2(st[qg][c4][3]);
                    rsum[qg] += (p0 + p1) + (p2 + p3);
                    uint2v pk;
                    pk[0] = pkbf(p0, p1);
                    pk[1] = pkbf(p2, p3);
                    pa[qg][c4] = pk;
                }
            }
            // PV: bv read once, used by both q-groups
            #pragma unroll
            for (int c2 = 0; c2 < 4; ++c2) {
                #pragma unroll
                for (int c4 = 0; c4 < 4; ++c4) {
                    const int c = cc * 4 + c4;
                    uint2v bv = *(const uint2v*)&Vs[(2 * c + (quad >> 1)) * 520
                                                    + (c2 * 16 + l16) * 8
                                                    + (quad & 1) * 4];
                    #pragma unroll
                    for (int qg = 0; qg < 2; ++qg)
                        o[qg][c2] = mfma16(pa[qg][c4], bv, o[qg][c2]);
                }
            }
        }
    }

    // full denom for q=l16: sum over the 4 quad-lanes
    #pragma unroll
    for (int qg = 0; qg < 2; ++qg) {
        rsum[qg] += __shfl_xor(rsum[qg], 16, 64);
        rsum[qg] += __shfl_xor(rsum[qg], 32, 64);
    }

    // epilogue: o rows are q=quad*4+r; fetch that q's denom from lane q
    #pragma unroll
    for (int qg = 0; qg < 2; ++qg) {
        #pragma unroll
        for (int r = 0; r < 4; ++r) {
            float inv = 1.0f / __shfl(rsum[qg], quad * 4 + r, 64);
            size_t row = rowbase + qb + wave * 32 + qg * 16 + quad * 4 + r;
            #pragma unroll
            for (int c2 = 0; c2 < 4; ++c2)
                qkv[row * 3072 + h * 64 + c2 * 16 + l16] = f2b(o[qg][c2][r] * inv);
        }
    }
}

// ---------------------------------------------------------------------------
extern "C" void kernel_launch(void* const* d_in, const int* in_sizes, int n_in,
                              void* d_out, int out_size, void* d_ws, size_t ws_size,
                              hipStream_t stream)
{
    const float* x    = (const float*)d_in[0];   // (2,2048,1024) fp32
    const float* Wqkv = (const float*)d_in[2];   // (1024,3072) fp32
    const float* Wout = (const float*)d_in[3];   // (1024,1024) fp32
    const float* bout = (const float*)d_in[4];   // (1024,) fp32
    float* out = (float*)d_out;                  // (2,2048,1024) fp32

    // Buffer map:
    //   ws (32 MiB): qkv 24 MiB | wqkvt 6 MiB | woutt 2 MiB
    //   d_out (16 MiB): xbf lower 8 MiB (dead after gemm1)
    //                   vt  upper 8 MiB (written by gemm1's fused epilogue,
    //                                    dead after attn)
    //   gemm2 overwrites all of d_out last.
    short* qkv   = (short*)d_ws;                        // 4096 x 3072 bf16
    short* wqkvt = qkv + (size_t)4096 * 3072;           // 3072 x 1024 bf16
    short* woutt = wqkvt + (size_t)3072 * 1024;         // 1024 x 1024 bf16
    short* xbf   = (short*)d_out;                       // 4096 x 1024 bf16
    short* vtbuf = xbf + (size_t)4096 * 1024;           // 32 x 64 x 2048 bf16

    dim3 blk(256);
    prep<<<dim3(3072), blk, 0, stream>>>(x, xbf, Wqkv, wqkvt, Wout, woutt);
    gemm128<true, short><<<dim3(24, 32), blk, 0, stream>>>(
        xbf, wqkvt, qkv, vtbuf, 2048, 4096, 3072, 1024, 1024);
    attn128<<<dim3(16, 32), blk, 0, stream>>>(qkv, vtbuf);
    gemm64<true, float><<<dim3(8, 64), blk, 0, stream>>>(
        qkv, woutt, bout, out, 4096, 1024, 1024, 3072);
}